// Round 11
// baseline (182.512 us; speedup 1.0000x reference)
//
#include <hip/hip_runtime.h>
#include <math.h>

#define B_ 8
#define L_ 1024
#define E_ 512
#define H_ 8
#define D_ 64
#define QSZ (B_*H_*L_*D_)          // 4,194,304 elements
#define BLE ((size_t)B_*L_*E_)     // 4,194,304
#define TINYF 1.175494350822287508e-38f
#define SWK(r) ((((r) ^ ((r) >> 3))) & 7)   // full-entropy LDS chunk swizzle key

typedef unsigned short u16;
typedef __attribute__((ext_vector_type(8))) short bfrag;    // 8 bf16 (4 VGPRs)
typedef __attribute__((ext_vector_type(4))) float ffrag;    // 4 fp32 acc (16x16)
typedef __attribute__((ext_vector_type(16))) float ffrag16; // 16 fp32 acc (32x32)
typedef __attribute__((ext_vector_type(4))) short vshort4;

#if __has_builtin(__builtin_amdgcn_exp2f)
#define EXP2F(x) __builtin_amdgcn_exp2f(x)
#else
#define EXP2F(x) __expf((x) * 0.6931471805599453f)
#endif
#if __has_builtin(__builtin_amdgcn_rcpf)
#define RCPF(x) __builtin_amdgcn_rcpf(x)
#else
#define RCPF(x) (1.0f / (x))
#endif

__device__ __forceinline__ u16 f2b(float f) {
  unsigned u = __float_as_uint(f);
  u += 0x7fffu + ((u >> 16) & 1u);           // RNE
  return (u16)(u >> 16);
}
__device__ __forceinline__ unsigned pk2(float a, float b) {  // lo=rne(a), hi=rne(b)
  unsigned ua = __float_as_uint(a); ua += 0x7fffu + ((ua >> 16) & 1u);
  unsigned ub = __float_as_uint(b); ub += 0x7fffu + ((ub >> 16) & 1u);
  return (ua >> 16) | (ub & 0xffff0000u);
}
__device__ __forceinline__ float blo(unsigned u) { return __uint_as_float(u << 16); }
__device__ __forceinline__ float bhi(unsigned u) { return __uint_as_float(u & 0xffff0000u); }

__device__ __forceinline__ bfrag cvt8v(const float* __restrict__ src) {
  float4 a = *(const float4*)src;
  float4 b = *(const float4*)(src + 4);
  bfrag r;
  r[0]=(short)f2b(a.x); r[1]=(short)f2b(a.y); r[2]=(short)f2b(a.z); r[3]=(short)f2b(a.w);
  r[4]=(short)f2b(b.x); r[5]=(short)f2b(b.y); r[6]=(short)f2b(b.z); r[7]=(short)f2b(b.w);
  return r;
}

// async global->LDS, 16B per lane; lds base wave-uniform (HW adds lane*16);
// GLOBAL src addr is per-lane -> usable as a row-gather with linear LDS dest.
__device__ __forceinline__ void gll16(const void* g, void* l) {
  __builtin_amdgcn_global_load_lds(
      (const __attribute__((address_space(1))) void*)g,
      (__attribute__((address_space(3))) void*)l, 16, 0, 0);
}

// ---- merged prep (fp32->bf16) + softmax(G) + per-batch mask compaction scan -
__global__ __launch_bounds__(256) void prep_softmax_k(
    const float* __restrict__ x, const float* __restrict__ Wq,
    const float* __restrict__ Wk, const float* __restrict__ Wv,
    const float* __restrict__ Wo, const float* __restrict__ G,
    const int* __restrict__ mask,
    u16* __restrict__ xb, u16* __restrict__ Wb, u16* __restrict__ actb,
    float* __restrict__ R, int* __restrict__ posb, int* __restrict__ nvb,
    int* __restrict__ itok) {
  const int bid = blockIdx.x, t = threadIdx.x;
  __shared__ float sred[8];
  __shared__ float rred[4][8];
  __shared__ int sc[256];
  if (bid < 2048) {
    size_t c = (size_t)bid * 256 + t;
    *(bfrag*)&xb[c * 8] = cvt8v(x + c * 8);
    return;
  }
  if (bid < 2560) {
    const int c2 = bid - 2048;
    const float* src = (c2 < 128) ? Wq : (c2 < 256) ? Wk : (c2 < 384) ? Wv : Wo;
    const size_t base = (size_t)(c2 >> 7) * 262144;
    const size_t cc = (size_t)(c2 & 127) * 256 + t;
    *(bfrag*)&Wb[base + cc * 8] = cvt8v(src + cc * 8);
    return;
  }
  if (bid >= 3584) {
    // ---- per-batch valid-first permutation + inverse (compact -> token) ----
    const int bb = bid - 3584;
    int4 mi = *(const int4*)(mask + bb * 1024 + t * 4);
    const int vx = mi.x ? 1 : 0, vy = mi.y ? 1 : 0;
    const int vz = mi.z ? 1 : 0, vw = mi.w ? 1 : 0;
    const int c0 = vx + vy + vz + vw;
    sc[t] = c0;
    __syncthreads();
#pragma unroll
    for (int off = 1; off < 256; off <<= 1) {
      int v = (t >= off) ? sc[t - off] : 0;
      __syncthreads();
      sc[t] += v;
      __syncthreads();
    }
    const int nvtot = sc[255];
    int pv = sc[t] - c0;          // valid tokens before this thread's 4
    int pi = t * 4 - pv;          // invalid tokens before
    int4 pq;
    pq.x = vx ? pv : nvtot + pi; pv += vx; pi += 1 - vx;
    pq.y = vy ? pv : nvtot + pi; pv += vy; pi += 1 - vy;
    pq.z = vz ? pv : nvtot + pi; pv += vz; pi += 1 - vz;
    pq.w = vw ? pv : nvtot + pi;
    *(int4*)(posb + bb * 1024 + t * 4) = pq;
    itok[bb * 1024 + pq.x] = t * 4;
    itok[bb * 1024 + pq.y] = t * 4 + 1;
    itok[bb * 1024 + pq.z] = t * 4 + 2;
    itok[bb * 1024 + pq.w] = t * 4 + 3;
    if (t == 0) nvb[bb] = nvtot;
    return;
  }
  const int q = bid - 2560;
  const int w = t >> 6, lane = t & 63;
  float4 g4 = ((const float4*)(G + (size_t)q * 1024))[t];
  float m = fmaxf(fmaxf(g4.x, g4.y), fmaxf(g4.z, g4.w));
#pragma unroll
  for (int off = 32; off > 0; off >>= 1) m = fmaxf(m, __shfl_down(m, off));
  if (lane == 0) sred[w] = m;
  __syncthreads();
  m = fmaxf(fmaxf(sred[0], sred[1]), fmaxf(sred[2], sred[3]));
  float e0 = __expf(g4.x - m), e1 = __expf(g4.y - m);
  float e2 = __expf(g4.z - m), e3 = __expf(g4.w - m);
  float s = e0 + e1 + e2 + e3;
#pragma unroll
  for (int off = 32; off > 0; off >>= 1) s += __shfl_down(s, off);
  if (lane == 0) sred[4 + w] = s;
  __syncthreads();
  const float inv = 1.0f / (sred[4] + sred[5] + sred[6] + sred[7]);
  const unsigned p0 = pk2(e0 * inv, e1 * inv);
  const unsigned p1 = pk2(e2 * inv, e3 * inv);
  *(uint2*)&actb[(size_t)q * 1024 + t * 4] = make_uint2(p0, p1);
  const float r0 = blo(p0), r1 = bhi(p0);
  const float r2 = blo(p1), r3 = bhi(p1);
  float rd[8];
#pragma unroll
  for (int b = 0; b < 8; ++b) {
    const int* mkp = mask + b * 1024 + t * 4;
    rd[b] = (mkp[0] ? r0 : 0.f) + (mkp[1] ? r1 : 0.f) +
            (mkp[2] ? r2 : 0.f) + (mkp[3] ? r3 : 0.f);
#pragma unroll
    for (int off = 32; off > 0; off >>= 1) rd[b] += __shfl_down(rd[b], off);
  }
  if (lane == 0)
#pragma unroll
    for (int b = 0; b < 8; ++b) rred[w][b] = rd[b];
  __syncthreads();
  if (t < 8) R[q * 8 + t] = rred[0][t] + rred[1][t] + rred[2][t] + rred[3][t];
}

// ---- QKV projection GEMM, 128x128 m97-shape tiles (R10 form, untouched) -----
// Q rows SCATTERED valid-first through posb; K and V stay token-space.
__global__ __launch_bounds__(256) void proj_k(
    const u16* __restrict__ xb, const u16* __restrict__ Wb,
    const int* __restrict__ mask, const float* __restrict__ R,
    const int* __restrict__ posb,
    float* __restrict__ sums,
    u16* __restrict__ Qb, u16* __restrict__ Kb, u16* __restrict__ Vtb) {
  const int m0 = blockIdx.x * 128;
  const int n0 = blockIdx.y * 128;
  __shared__ __align__(16) u16 As[128 * 64];
  __shared__ __align__(16) u16 Bs[128 * 64];
  __shared__ float rr[4][8];
  const int t = threadIdx.x, w = t >> 6, lane = t & 63;
  const int l15 = lane & 15, quad = lane >> 4;
  const int mq = (w >> 1) * 64, nq = (w & 1) * 64;

  if (blockIdx.x == 0 && blockIdx.y == 0) {   // gsums + denom-zero (hidden)
    float a8[8] = {0,0,0,0,0,0,0,0};
    for (int q = t; q < 1024; q += 256)
#pragma unroll
      for (int b = 0; b < 8; ++b)
        if (mask[b * 1024 + q]) a8[b] += R[q * 8 + b];
#pragma unroll
    for (int b = 0; b < 8; ++b) {
#pragma unroll
      for (int off = 32; off > 0; off >>= 1) a8[b] += __shfl_down(a8[b], off);
    }
    if (lane == 0)
#pragma unroll
      for (int b = 0; b < 8; ++b) rr[w][b] = a8[b];
    __syncthreads();
    if (t < 8) {
      sums[t] = 0.0f;
      sums[8 + t] = rr[0][t] + rr[1][t] + rr[2][t] + rr[3][t];
    }
  }

  const ffrag fz = {0.f, 0.f, 0.f, 0.f};
  ffrag acc[4][4];
#pragma unroll
  for (int i = 0; i < 4; ++i)
#pragma unroll
    for (int j = 0; j < 4; ++j) acc[i][j] = fz;

  for (int kk = 0; kk < 512; kk += 64) {
    __syncthreads();
#pragma unroll
    for (int j = 0; j < 4; ++j) {
      const int c = w * 256 + j * 64 + lane;
      const int row = c >> 3, ck = (c & 7) ^ (row & 7);
      gll16(xb + (size_t)(m0 + row) * 512 + kk + ck * 8,
            &As[(size_t)(w * 256 + j * 64) * 8]);
    }
#pragma unroll
    for (int j = 0; j < 4; ++j) {
      const int c = w * 256 + j * 64 + lane;
      const int row = c >> 3, ck = (c & 7) ^ (row & 7);
      gll16(Wb + (size_t)(n0 + row) * 512 + kk + ck * 8,
            &Bs[(size_t)(w * 256 + j * 64) * 8]);
    }
    __syncthreads();
#pragma unroll
    for (int s = 0; s < 2; ++s) {
      bfrag av[4], bv[4];
#pragma unroll
      for (int i = 0; i < 4; ++i) {
        const int ar = mq + i * 16 + l15;
        av[i] = *(const bfrag*)&As[ar * 64 + (((quad + 4 * s) ^ (ar & 7)) << 3)];
        const int br = nq + i * 16 + l15;
        bv[i] = *(const bfrag*)&Bs[br * 64 + (((quad + 4 * s) ^ (br & 7)) << 3)];
      }
#pragma unroll
      for (int i = 0; i < 4; ++i)
#pragma unroll
        for (int j = 0; j < 4; ++j)
          acc[i][j] = __builtin_amdgcn_mfma_f32_16x16x32_bf16(av[i], bv[j], acc[i][j], 0, 0, 0);
    }
  }
  const int z = n0 >> 9;          // which of Wq/Wk/Wv (128 | 512)
  const int c0 = n0 & 511;
#pragma unroll
  for (int i = 0; i < 4; ++i) {
    const int mbase = m0 + mq + i * 16 + quad * 4;
    const int b = mbase >> 10, l0 = mbase & 1023;
    int4 pr;
    if (z == 0) pr = *(const int4*)(posb + b * 1024 + l0);   // l0 % 4 == 0
#pragma unroll
    for (int j = 0; j < 4; ++j) {
      const int nc = c0 + nq + j * 16 + l15;
      const int h = nc >> 6, d = nc & 63;
      if (z == 0) {
        u16* dst = Qb + (size_t)(b * 8 + h) * 65536 + d;
        dst[(size_t)pr.x * 64] = f2b(acc[i][j][0]);
        dst[(size_t)pr.y * 64] = f2b(acc[i][j][1]);
        dst[(size_t)pr.z * 64] = f2b(acc[i][j][2]);
        dst[(size_t)pr.w * 64] = f2b(acc[i][j][3]);
      } else if (z == 1) {
        u16* dst = Kb + ((size_t)(b * 8 + h) * 1024 + l0) * 64 + d;
#pragma unroll
        for (int r = 0; r < 4; ++r) dst[(size_t)r * 64] = f2b(acc[i][j][r]);
      } else {
        vshort4 vs;
#pragma unroll
        for (int r = 0; r < 4; ++r)
          vs[r] = (short)(mask[b * 1024 + l0 + r] ? f2b(acc[i][j][r]) : (u16)0);
        *(vshort4*)(Vtb + ((size_t)(b * 8 + h) * 64 + d) * 1024 + l0) = vs;
      }
    }
  }
}

// ---- fused grid, R5 XCD-batch mapping + R7 attn q-compaction ----------------
// R11: + G-path q-compaction (the clean piece of R8). G blocks GATHER valid
// act rows via per-lane gll16 global addrs (itok) and exit when q0 >= nv
// (~half of 64 G blocks/XCD): G work 8.6 -> ~4.5 GF. AG written compact-row;
// o_proj gathers AG with the same prw index as AE. Dot products bitwise
// identical (rows reordered only; B operand stays token-space Vtb). R8's
// proj-side Vc/K scatter (the actual regression source) NOT re-added.
__global__ __launch_bounds__(256) void attn_gv_k(
    const u16* __restrict__ Qb, const u16* __restrict__ Kb,
    const u16* __restrict__ Vtb, const u16* __restrict__ actb,
    const int* __restrict__ mask, const int* __restrict__ nvb,
    const int* __restrict__ itok,
    u16* __restrict__ AEb, u16* __restrict__ AGb, float* __restrict__ denom) {
  __shared__ __align__(16) u16 POOL[13320];   // 26.6 KB
  const int t = threadIdx.x, w = t >> 6, lane = t & 63;
  const int l15 = lane & 15, quad = lane >> 4;
  const int X = blockIdx.x & 7;      // XCD id (round-robin dispatch, m09)
  const int s = blockIdx.x >> 3;     // slot on this XCD [0,192)
  const int s3 = s % 3, sd3 = s / 3;

  if (s3 == 2) {
    // ---- G-path GEMM (compact q): AG[(X*1024+qc)][n] =
    //      sum_k act[tok(qc)][k] * Vtb[X*512+n][k]
    u16* As = POOL;           // 64 rows x 64 k  (8 KB)
    u16* Bs = POOL + 4096;    // 128 rows x 64 k (16 KB)
    const int b = X;
    const int q0 = (sd3 >> 2) * 64;          // 16 q-tiles
    const int n0 = (sd3 & 3) * 128;          // 4 n-tiles
    const int nv = nvb[b];
    if (q0 >= nv) return;                    // whole tile is discarded rows
    const int* it = itok + b * 1024;
    const int m0 = b * 1024 + q0;            // compact AGb row base
    const int mq = (w >> 1) * 32, nq = (w & 1) * 64;
    const ffrag fz = {0.f, 0.f, 0.f, 0.f};
    ffrag acc[2][4];
#pragma unroll
    for (int i = 0; i < 2; ++i)
#pragma unroll
      for (int j = 0; j < 4; ++j) acc[i][j] = fz;

    // per-lane act row gather indices (2 stage instrs -> 2 rows/lane)
    int tokr[2];
#pragma unroll
    for (int j = 0; j < 2; ++j) {
      const int c = w * 128 + j * 64 + lane;
      tokr[j] = it[q0 + (c >> 3)];
    }

    for (int kk = 0; kk < 1024; kk += 64) {
      __syncthreads();
#pragma unroll
      for (int j = 0; j < 2; ++j) {            // A: gathered valid rows
        const int c = w * 128 + j * 64 + lane;
        const int row = c >> 3, ck = (c & 7) ^ (row & 7);
        gll16(actb + (size_t)tokr[j] * 1024 + kk + ck * 8,
              &As[(size_t)(w * 128 + j * 64) * 8]);
      }
#pragma unroll
      for (int j = 0; j < 4; ++j) {            // B: 1024 16B chunks
        const int c = w * 256 + j * 64 + lane;
        const int row = c >> 3, ck = (c & 7) ^ (row & 7);
        gll16(Vtb + (size_t)(b * 512 + n0 + row) * 1024 + kk + ck * 8,
              &Bs[(size_t)(w * 256 + j * 64) * 8]);
      }
      __syncthreads();
#pragma unroll
      for (int sgm = 0; sgm < 2; ++sgm) {
        bfrag av[2], bv[4];
#pragma unroll
        for (int i = 0; i < 2; ++i) {
          const int ar = mq + i * 16 + l15;
          av[i] = *(const bfrag*)&As[ar * 64 + (((quad + 4 * sgm) ^ (ar & 7)) << 3)];
        }
#pragma unroll
        for (int j = 0; j < 4; ++j) {
          const int br = nq + j * 16 + l15;
          bv[j] = *(const bfrag*)&Bs[br * 64 + (((quad + 4 * sgm) ^ (br & 7)) << 3)];
        }
#pragma unroll
        for (int i = 0; i < 2; ++i)
#pragma unroll
          for (int j = 0; j < 4; ++j)
            acc[i][j] = __builtin_amdgcn_mfma_f32_16x16x32_bf16(av[i], bv[j], acc[i][j], 0, 0, 0);
      }
    }
#pragma unroll
    for (int i = 0; i < 2; ++i) {
      const int mbase = m0 + mq + i * 16 + quad * 4;     // compact row
#pragma unroll
      for (int j = 0; j < 4; ++j) {
        const int n = n0 + nq + j * 16 + l15;
#pragma unroll
        for (int r = 0; r < 4; ++r)
          AGb[(size_t)(mbase + r) * 512 + n] = f2b(acc[i][j][r]);
      }
    }
    return;
  }

  // ---- attention E-path: a = 2*sd3 + s3 in [0,128); compacted q space ----
  const int a_ = sd3 * 2 + s3;
  const int qt = a_ & 15;
  const int h = a_ >> 4;
  const int b = X;
  const int bh = X * 8 + h;
  const int nv = nvb[b];
  if (qt * 64 >= nv) return;          // tile entirely masked-q: no output used
  u16* Ks = POOL;             // 8 KB [k][d]
  u16* Vs = POOL + 4096;      // 8 KB [d][k]
  u16* Es = POOL + 8192;      // 8 KB [q][k]
  u16* Ms = POOL + 12288;     // 2 KB bf16 mask
  float* red4 = (float*)(POOL + 13312);
  const int l31 = lane & 31, hi = lane >> 5;
  const int qsb = w >> 1, msb = w & 1;   // S-phase: q-block, k(m)-block
  const int qpb = w & 1, dpb = w >> 1;   // PV-phase: q-block, d-block (distinct!)

  const u16* Kg = Kb + (size_t)bh * 65536;
  const u16* Vg = Vtb + (size_t)bh * 65536;

  const u16* Qrow = Qb + ((size_t)bh * 1024 + qt * 64 + qsb * 32 + l31) * 64;
  bfrag qf[4];
#pragma unroll
  for (int ko = 0; ko < 4; ++ko) qf[ko] = *(const bfrag*)(Qrow + ko * 16 + hi * 8);

  {
    int4 mi = *(const int4*)(mask + b * 1024 + t * 4);
    vshort4 mv;
    mv[0] = mi.x ? (short)0x3F80 : (short)0; mv[1] = mi.y ? (short)0x3F80 : (short)0;
    mv[2] = mi.z ? (short)0x3F80 : (short)0; mv[3] = mi.w ? (short)0x3F80 : (short)0;
    *(vshort4*)&Ms[t * 4] = mv;
  }

  auto stageK = [&](int kt) {
#pragma unroll
    for (int j = 0; j < 2; ++j) {
      const int c = w * 128 + j * 64 + lane;
      const int row = c >> 3, ck = (c & 7) ^ SWK(row);
      gll16(Kg + (size_t)(kt * 64 + row) * 64 + ck * 8,
            &Ks[(size_t)(w * 128 + j * 64) * 8]);
    }
  };
  auto stageV = [&](int kt) {
#pragma unroll
    for (int j = 0; j < 2; ++j) {
      const int c = w * 128 + j * 64 + lane;
      const int row = c >> 3, ck = (c & 7) ^ SWK(row);
      gll16(Vg + (size_t)row * 1024 + kt * 64 + ck * 8,
            &Vs[(size_t)(w * 128 + j * 64) * 8]);
    }
  };

  stageK(0); stageV(0);
  __syncthreads();

  ffrag16 accE, dacc;
#pragma unroll
  for (int i = 0; i < 16; ++i) { accE[i] = 0.f; dacc[i] = 0.f; }

  for (int kt = 0; kt < 16; ++kt) {
    // ---- S-phase: S^T block (m = wave's 32-k block, n = its 32-q block) ----
    ffrag16 st;
#pragma unroll
    for (int i = 0; i < 16; ++i) st[i] = 0.f;
    const int krow = msb * 32 + l31;
    const int kk7 = SWK(krow);
#pragma unroll
    for (int ko = 0; ko < 4; ++ko) {
      bfrag ak = *(const bfrag*)&Ks[krow * 64 + (((ko * 2 + hi) ^ kk7) << 3)];
      st = __builtin_amdgcn_mfma_f32_32x32x16_bf16(ak, qf[ko], st, 0, 0, 0);
    }
    // ---- nonlinearity -> Es (lane = q col; reg r -> k-local) ----
    const int qrow = qsb * 32 + l31;
    const int qk7 = SWK(qrow);
#pragma unroll
    for (int g = 0; g < 4; ++g) {
      float ee[4];
#pragma unroll
      for (int r = 0; r < 4; ++r) {
        const float tt = EXP2F(st[4 * g + r] * 0.360673760222f);
        ee[r] = EXP2F(RCPF(tt + 1.0f) * -2.88539008178f);
      }
      const int k0 = msb * 32 + g * 8 + hi * 4;
      *(uint2*)&Es[qrow * 64 + (((k0 >> 3) ^ qk7) << 3) + (k0 & 7)] =
          make_uint2(pk2(ee[0], ee[1]), pk2(ee[2], ee[3]));
    }
    __syncthreads();                   // Es visible; Ks reads done blockwide
    if (kt < 15) stageK(kt + 1);       // drains at next barrier

    // ---- PV: distinct quadrant per wave (E-path + denominator only) ----
    const int erow = qpb * 32 + l31;
    const int ek7 = SWK(erow);
    const int vrow = dpb * 32 + l31;
    const int vk7 = SWK(vrow);
#pragma unroll
    for (int ko = 0; ko < 4; ++ko) {
      const int co = ko * 2 + hi;
      bfrag ea = *(const bfrag*)&Es[erow * 64 + ((co ^ ek7) << 3)];
      bfrag bv = *(const bfrag*)&Vs[vrow * 64 + ((co ^ vk7) << 3)];
      accE = __builtin_amdgcn_mfma_f32_32x32x16_bf16(ea, bv, accE, 0, 0, 0);
      if (dpb == 0) {
        bfrag bm = *(const bfrag*)&Ms[kt * 64 + ko * 16 + hi * 8];
        dacc = __builtin_amdgcn_mfma_f32_32x32x16_bf16(ea, bm, dacc, 0, 0, 0);
      }
    }
    __syncthreads();                   // Vs/Es reads done; stageK drained
    if (kt < 15) stageV(kt + 1);
  }

  // ---- epilogue: wave stores its (qpb, dpb) quadrant of AE (compacted rows) -
  const size_t obase = ((size_t)(b * 1024 + qt * 64 + qpb * 32)) * 512
                       + h * 64 + dpb * 32 + l31;
#pragma unroll
  for (int r = 0; r < 16; ++r) {
    const int qloc = (r & 3) + 8 * (r >> 2) + 4 * hi;
    AEb[obase + (size_t)qloc * 512] = f2b(accE[r]);
  }
  // ---- denominator: q-filter is compact index < nv (valid-first order) ----
  float dsumv = 0.0f;
  if (l31 == 0 && dpb == 0) {
    const int cq0 = qt * 64 + qpb * 32 + 4 * hi;
#pragma unroll
    for (int r = 0; r < 16; ++r) {
      const int cq = cq0 + (r & 3) + 8 * (r >> 2);
      dsumv += (cq < nv) ? dacc[r] : 0.0f;
    }
    red4[qpb * 2 + hi] = dsumv;
  }
  __syncthreads();
  if (t == 0) atomicAdd(denom + b, red4[0] + red4[1] + red4[2] + red4[3]);
}

// ---- out = (mq*(c1*AE[pos] + c2*AG[pos])) @ Wo^T, 128x128 tiles -------------
__global__ __launch_bounds__(256) void o_proj_k(
    const u16* __restrict__ AEb, const u16* __restrict__ AGb,
    const int* __restrict__ mask, const int* __restrict__ posb,
    const float* __restrict__ sums,
    const u16* __restrict__ Wb, float* __restrict__ out) {
  const int m0 = blockIdx.x * 128;
  const int n0 = blockIdx.y * 128;
  const int b = m0 >> 10;
  const float c1 = 0.5f / fmaxf(sums[b], TINYF);
  const float c2 = 0.5f / fmaxf(sums[8 + b], TINYF);
  __shared__ __align__(16) u16 As[128 * 64];
  __shared__ __align__(16) u16 Bs[128 * 64];
  const int t = threadIdx.x, w = t >> 6, lane = t & 63;
  const int l15 = lane & 15, quad = lane >> 4;
  const int mq = (w >> 1) * 64, nq = (w & 1) * 64;
  int rowi[4], prw[4], mrow[4]; float c1r[4], c2r[4];
#pragma unroll
  for (int i = 0; i < 4; ++i) {
    const int c = t + i * 256;
    rowi[i] = c >> 3;
    const int tok = (m0 + rowi[i]) & 1023;
    mrow[i] = mask[b * 1024 + tok];
    prw[i] = posb[b * 1024 + tok];        // compacted row for this token
    c1r[i] = mrow[i] ? c1 : 0.0f;
    c2r[i] = mrow[i] ? c2 : 0.0f;
  }
  const ffrag fz = {0.f, 0.f, 0.f, 0.f};
  ffrag acc[4][4];
#pragma unroll
  for (int i = 0; i < 4; ++i)
#pragma unroll
    for (int j = 0; j < 4; ++j) acc[i][j] = fz;

  for (int kk = 0; kk < 512; kk += 64) {
    __syncthreads();
#pragma unroll
    for (int i = 0; i < 4; ++i) {
      const int c = t + i * 256;
      const int row = rowi[i], ck = c & 7;
      const size_t gofsE = (size_t)(b * 1024 + prw[i]) * 512 + kk + ck * 8;
      uint4 ua = *(const uint4*)(AEb + gofsE);
      uint4 ug = *(const uint4*)(AGb + gofsE);
      if (!mrow[i]) {                       // garbage rows: NaN-safe zero
        ua = make_uint4(0u, 0u, 0u, 0u);
        ug = make_uint4(0u, 0u, 0u, 0u);
      }
      const float a1 = c1r[i], a2 = c2r[i];
      uint4 res;
      res.x = pk2(a1 * blo(ua.x) + a2 * blo(ug.x), a1 * bhi(ua.x) + a2 * bhi(ug.x));
      res.y = pk2(a1 * blo(ua.y) + a2 * blo(ug.y), a1 * bhi(ua.y) + a2 * bhi(ug.y));
      res.z = pk2(a1 * blo(ua.z) + a2 * blo(ug.z), a1 * bhi(ua.z) + a2 * bhi(ug.z));
      res.w = pk2(a1 * blo(ua.w) + a2 * blo(ug.w), a1 * bhi(ua.w) + a2 * bhi(ug.w));
      *(uint4*)&As[row * 64 + ((ck ^ (row & 7)) << 3)] = res;
    }
#pragma unroll
    for (int j = 0; j < 4; ++j) {
      const int c = w * 256 + j * 64 + lane;
      const int row = c >> 3, ck = (c & 7) ^ (row & 7);
      gll16(Wb + (size_t)(1536 + n0 + row) * 512 + kk + ck * 8,
            &Bs[(size_t)(w * 256 + j * 64) * 8]);
    }
    __syncthreads();
#pragma unroll
    for (int s = 0; s < 2; ++s) {
      bfrag av[4], bv[4];
#pragma unroll
      for (int i = 0; i < 4; ++i) {
        const int ar = mq + i * 16 + l15;
        av[i] = *(const bfrag*)&As[ar * 64 + (((quad + 4 * s) ^ (ar & 7)) << 3)];
        const int br = nq + i * 16 + l15;
        bv[i] = *(const bfrag*)&Bs[br * 64 + (((quad + 4 * s) ^ (br & 7)) << 3)];
      }
#pragma unroll
      for (int i = 0; i < 4; ++i)
#pragma unroll
        for (int j = 0; j < 4; ++j)
          acc[i][j] = __builtin_amdgcn_mfma_f32_16x16x32_bf16(av[i], bv[j], acc[i][j], 0, 0, 0);
    }
  }
#pragma unroll
  for (int i = 0; i < 4; ++i) {
    const int mbase = m0 + mq + i * 16 + quad * 4;
#pragma unroll
    for (int j = 0; j < 4; ++j) {
      const int n = n0 + nq + j * 16 + l15;
#pragma unroll
      for (int r = 0; r < 4; ++r)
        out[(size_t)(mbase + r) * 512 + n] = acc[i][j][r];
    }
  }
}

extern "C" void kernel_launch(void* const* d_in, const int* in_sizes, int n_in,
                              void* d_out, int out_size, void* d_ws, size_t ws_size,
                              hipStream_t stream) {
  const float* x  = (const float*)d_in[0];
  const int* mask = (const int*)d_in[1];
  const float* Wq = (const float*)d_in[2];
  const float* Wk = (const float*)d_in[3];
  const float* Wv = (const float*)d_in[4];
  const float* Wo = (const float*)d_in[5];
  const float* G  = (const float*)d_in[6];
  float* out = (float*)d_out;

  u16* xb   = (u16*)d_ws;                    // 8192*512
  u16* Wb   = xb + (size_t)8192 * 512;       // 2048*512
  u16* Qb   = Wb + (size_t)2048 * 512;       // QSZ (compacted rows per batch)
  u16* Kb   = Qb + QSZ;                      // token space
  u16* Vtb  = Kb + QSZ;                      // token space
  u16* actb = Vtb + QSZ;                     // 1024*1024
  u16* AEb  = actb + (size_t)1024 * 1024;    // BLE (compacted rows per batch)
  u16* AGb  = AEb + BLE;                     // BLE (compacted rows per batch)
  float* R  = (float*)(AGb + BLE);           // 1024*8
  float* SUMS = R + 8192;                    // denom[8], gsums[8]
  int* posb = (int*)(SUMS + 16);             // 8*1024 token->compact position
  int* nvb  = posb + 8192;                   // 8 valid counts
  int* itok = nvb + 8;                       // 8*1024 compact->token (inverse)

  prep_softmax_k<<<3592, 256, 0, stream>>>(x, Wq, Wk, Wv, Wo, G, mask, xb, Wb, actb, R, posb, nvb, itok);
  proj_k<<<dim3(64, 12), 256, 0, stream>>>(xb, Wb, mask, R, posb, SUMS, Qb, Kb, Vtb);
  attn_gv_k<<<1536, 256, 0, stream>>>(Qb, Kb, Vtb, actb, mask, nvb, itok, AEb, AGb, SUMS);
  o_proj_k<<<dim3(64, 4), 256, 0, stream>>>(AEb, AGb, mask, nvb ? posb : posb, SUMS, Wb, out);
}

// Round 12
// 173.887 us; speedup vs baseline: 1.0496x; 1.0496x over previous
//
#include <hip/hip_runtime.h>
#include <math.h>

#define B_ 8
#define L_ 1024
#define E_ 512
#define H_ 8
#define D_ 64
#define QSZ (B_*H_*L_*D_)          // 4,194,304 elements
#define BLE ((size_t)B_*L_*E_)     // 4,194,304
#define TINYF 1.175494350822287508e-38f
#define SWK(r) ((((r) ^ ((r) >> 3))) & 7)   // full-entropy LDS chunk swizzle key

typedef unsigned short u16;
typedef __attribute__((ext_vector_type(8))) short bfrag;    // 8 bf16 (4 VGPRs)
typedef __attribute__((ext_vector_type(4))) float ffrag;    // 4 fp32 acc (16x16)
typedef __attribute__((ext_vector_type(16))) float ffrag16; // 16 fp32 acc (32x32)
typedef __attribute__((ext_vector_type(4))) short vshort4;

#if __has_builtin(__builtin_amdgcn_exp2f)
#define EXP2F(x) __builtin_amdgcn_exp2f(x)
#else
#define EXP2F(x) __expf((x) * 0.6931471805599453f)
#endif
#if __has_builtin(__builtin_amdgcn_rcpf)
#define RCPF(x) __builtin_amdgcn_rcpf(x)
#else
#define RCPF(x) (1.0f / (x))
#endif

__device__ __forceinline__ u16 f2b(float f) {
  unsigned u = __float_as_uint(f);
  u += 0x7fffu + ((u >> 16) & 1u);           // RNE
  return (u16)(u >> 16);
}
__device__ __forceinline__ unsigned pk2(float a, float b) {  // lo=rne(a), hi=rne(b)
  unsigned ua = __float_as_uint(a); ua += 0x7fffu + ((ua >> 16) & 1u);
  unsigned ub = __float_as_uint(b); ub += 0x7fffu + ((ub >> 16) & 1u);
  return (ua >> 16) | (ub & 0xffff0000u);
}
__device__ __forceinline__ float blo(unsigned u) { return __uint_as_float(u << 16); }
__device__ __forceinline__ float bhi(unsigned u) { return __uint_as_float(u & 0xffff0000u); }

__device__ __forceinline__ bfrag cvt8v(const float* __restrict__ src) {
  float4 a = *(const float4*)src;
  float4 b = *(const float4*)(src + 4);
  bfrag r;
  r[0]=(short)f2b(a.x); r[1]=(short)f2b(a.y); r[2]=(short)f2b(a.z); r[3]=(short)f2b(a.w);
  r[4]=(short)f2b(b.x); r[5]=(short)f2b(b.y); r[6]=(short)f2b(b.z); r[7]=(short)f2b(b.w);
  return r;
}

// async global->LDS, 16B per lane; lds base wave-uniform (HW adds lane*16);
// GLOBAL src addr is per-lane -> usable as a row-gather with linear LDS dest.
__device__ __forceinline__ void gll16(const void* g, void* l) {
  __builtin_amdgcn_global_load_lds(
      (const __attribute__((address_space(1))) void*)g,
      (__attribute__((address_space(3))) void*)l, 16, 0, 0);
}

// ---- prep: fp32->bf16 conversions + per-batch mask scan (+denom zero) -------
// R12: G-softmax MOVED to the proj launch (no prep dependency) so it overlaps
// proj's latency-bound GEMM blocks (m114 co-scheduling, R1-verified).
__global__ __launch_bounds__(256) void prep_k(
    const float* __restrict__ x, const float* __restrict__ Wq,
    const float* __restrict__ Wk, const float* __restrict__ Wv,
    const float* __restrict__ Wo, const int* __restrict__ mask,
    u16* __restrict__ xb, u16* __restrict__ Wb,
    int* __restrict__ posb, int* __restrict__ nvb, int* __restrict__ itok,
    float* __restrict__ sums) {
  const int bid = blockIdx.x, t = threadIdx.x;
  __shared__ int sc[256];
  if (bid < 2048) {
    size_t c = (size_t)bid * 256 + t;
    *(bfrag*)&xb[c * 8] = cvt8v(x + c * 8);
    return;
  }
  if (bid < 2560) {
    const int c2 = bid - 2048;
    const float* src = (c2 < 128) ? Wq : (c2 < 256) ? Wk : (c2 < 384) ? Wv : Wo;
    const size_t base = (size_t)(c2 >> 7) * 262144;
    const size_t cc = (size_t)(c2 & 127) * 256 + t;
    *(bfrag*)&Wb[base + cc * 8] = cvt8v(src + cc * 8);
    return;
  }
  // ---- per-batch valid-first permutation + inverse + denom zero ----
  const int bb = bid - 2560;
  int4 mi = *(const int4*)(mask + bb * 1024 + t * 4);
  const int vx = mi.x ? 1 : 0, vy = mi.y ? 1 : 0;
  const int vz = mi.z ? 1 : 0, vw = mi.w ? 1 : 0;
  const int c0 = vx + vy + vz + vw;
  sc[t] = c0;
  __syncthreads();
#pragma unroll
  for (int off = 1; off < 256; off <<= 1) {
    int v = (t >= off) ? sc[t - off] : 0;
    __syncthreads();
    sc[t] += v;
    __syncthreads();
  }
  const int nvtot = sc[255];
  int pv = sc[t] - c0;          // valid tokens before this thread's 4
  int pi = t * 4 - pv;          // invalid tokens before
  int4 pq;
  pq.x = vx ? pv : nvtot + pi; pv += vx; pi += 1 - vx;
  pq.y = vy ? pv : nvtot + pi; pv += vy; pi += 1 - vy;
  pq.z = vz ? pv : nvtot + pi; pv += vz; pi += 1 - vz;
  pq.w = vw ? pv : nvtot + pi;
  *(int4*)(posb + bb * 1024 + t * 4) = pq;
  itok[bb * 1024 + pq.x] = t * 4;
  itok[bb * 1024 + pq.y] = t * 4 + 1;
  itok[bb * 1024 + pq.z] = t * 4 + 2;
  itok[bb * 1024 + pq.w] = t * 4 + 3;
  if (t == 0) { nvb[bb] = nvtot; sums[bb] = 0.0f; }
}

// ---- fused launch 2: [0,1024) G-softmax blocks, [1024,1792) QKV GEMM --------
// Softmax blocks (G+mask only; write actb,R) overlap the latency-bound GEMM.
// GEMM: Q-blocks (z==0) GATHER valid x rows via per-lane gll16 (itok,
// R11-verified), exit when the tile is past nv (~47%), and store Q CONTIGUOUS
// (output row = compact index; posb scatter deleted). K/V blocks unchanged.
__global__ __launch_bounds__(256) void proj_k(
    const u16* __restrict__ xb, const u16* __restrict__ Wb,
    const float* __restrict__ G, const int* __restrict__ mask,
    const int* __restrict__ nvb, const int* __restrict__ itok,
    u16* __restrict__ actb, float* __restrict__ R,
    u16* __restrict__ Qb, u16* __restrict__ Kb, u16* __restrict__ Vtb) {
  const int bid = blockIdx.x, t = threadIdx.x;
  __shared__ __align__(16) u16 As[128 * 64];
  __shared__ __align__(16) u16 Bs[128 * 64];
  __shared__ float sred[8];
  __shared__ float rred[4][8];
  const int w = t >> 6, lane = t & 63;

  if (bid < 1024) {
    // ---- G-softmax (relocated from prep; code verbatim) ----
    const int q = bid;
    float4 g4 = ((const float4*)(G + (size_t)q * 1024))[t];
    float m = fmaxf(fmaxf(g4.x, g4.y), fmaxf(g4.z, g4.w));
#pragma unroll
    for (int off = 32; off > 0; off >>= 1) m = fmaxf(m, __shfl_down(m, off));
    if (lane == 0) sred[w] = m;
    __syncthreads();
    m = fmaxf(fmaxf(sred[0], sred[1]), fmaxf(sred[2], sred[3]));
    float e0 = __expf(g4.x - m), e1 = __expf(g4.y - m);
    float e2 = __expf(g4.z - m), e3 = __expf(g4.w - m);
    float s = e0 + e1 + e2 + e3;
#pragma unroll
    for (int off = 32; off > 0; off >>= 1) s += __shfl_down(s, off);
    if (lane == 0) sred[4 + w] = s;
    __syncthreads();
    const float inv = 1.0f / (sred[4] + sred[5] + sred[6] + sred[7]);
    const unsigned p0 = pk2(e0 * inv, e1 * inv);
    const unsigned p1 = pk2(e2 * inv, e3 * inv);
    *(uint2*)&actb[(size_t)q * 1024 + t * 4] = make_uint2(p0, p1);
    const float r0 = blo(p0), r1 = bhi(p0);
    const float r2 = blo(p1), r3 = bhi(p1);
    float rd[8];
#pragma unroll
    for (int b = 0; b < 8; ++b) {
      const int* mkp = mask + b * 1024 + t * 4;
      rd[b] = (mkp[0] ? r0 : 0.f) + (mkp[1] ? r1 : 0.f) +
              (mkp[2] ? r2 : 0.f) + (mkp[3] ? r3 : 0.f);
#pragma unroll
      for (int off = 32; off > 0; off >>= 1) rd[b] += __shfl_down(rd[b], off);
    }
    if (lane == 0)
#pragma unroll
      for (int b = 0; b < 8; ++b) rred[w][b] = rd[b];
    __syncthreads();
    if (t < 8) R[q * 8 + t] = rred[0][t] + rred[1][t] + rred[2][t] + rred[3][t];
    return;
  }

  // ---- QKV GEMM, 128x128 m97-shape tiles (gid = bid-1024, x fastest) ----
  const int gid = bid - 1024;
  const int m0 = (gid & 63) * 128;
  const int n0 = (gid >> 6) * 128;
  const int l15 = lane & 15, quad = lane >> 4;
  const int mq = (w >> 1) * 64, nq = (w & 1) * 64;
  const int z = n0 >> 9;          // 0=Q 1=K 2=V
  const int b = m0 >> 10, q0c = m0 & 1023;

  int tokr[4];
  if (z == 0) {
    const int nv = nvb[b];
    if (q0c >= nv) return;        // tile entirely discarded rows
    const int* it = itok + b * 1024;
#pragma unroll
    for (int j = 0; j < 4; ++j) {
      const int c = w * 256 + j * 64 + lane;
      tokr[j] = b * 1024 + it[q0c + (c >> 3)];
    }
  } else {
#pragma unroll
    for (int j = 0; j < 4; ++j) {
      const int c = w * 256 + j * 64 + lane;
      tokr[j] = m0 + (c >> 3);
    }
  }

  const ffrag fz = {0.f, 0.f, 0.f, 0.f};
  ffrag acc[4][4];
#pragma unroll
  for (int i = 0; i < 4; ++i)
#pragma unroll
    for (int j = 0; j < 4; ++j) acc[i][j] = fz;

  for (int kk = 0; kk < 512; kk += 64) {
    __syncthreads();
#pragma unroll
    for (int j = 0; j < 4; ++j) {
      const int c = w * 256 + j * 64 + lane;
      const int row = c >> 3, ck = (c & 7) ^ (row & 7);
      gll16(xb + (size_t)tokr[j] * 512 + kk + ck * 8,
            &As[(size_t)(w * 256 + j * 64) * 8]);
    }
#pragma unroll
    for (int j = 0; j < 4; ++j) {
      const int c = w * 256 + j * 64 + lane;
      const int row = c >> 3, ck = (c & 7) ^ (row & 7);
      gll16(Wb + (size_t)(n0 + row) * 512 + kk + ck * 8,
            &Bs[(size_t)(w * 256 + j * 64) * 8]);
    }
    __syncthreads();
#pragma unroll
    for (int s = 0; s < 2; ++s) {
      bfrag av[4], bv[4];
#pragma unroll
      for (int i = 0; i < 4; ++i) {
        const int ar = mq + i * 16 + l15;
        av[i] = *(const bfrag*)&As[ar * 64 + (((quad + 4 * s) ^ (ar & 7)) << 3)];
        const int br = nq + i * 16 + l15;
        bv[i] = *(const bfrag*)&Bs[br * 64 + (((quad + 4 * s) ^ (br & 7)) << 3)];
      }
#pragma unroll
      for (int i = 0; i < 4; ++i)
#pragma unroll
        for (int j = 0; j < 4; ++j)
          acc[i][j] = __builtin_amdgcn_mfma_f32_16x16x32_bf16(av[i], bv[j], acc[i][j], 0, 0, 0);
    }
  }
  const int c0 = n0 & 511;
#pragma unroll
  for (int i = 0; i < 4; ++i) {
    const int mbase = m0 + mq + i * 16 + quad * 4;
    const int l0 = mbase & 1023;         // compact row (z==0) / token (z>0)
#pragma unroll
    for (int j = 0; j < 4; ++j) {
      const int nc = c0 + nq + j * 16 + l15;
      const int h = nc >> 6, d = nc & 63;
      if (z == 0) {
        u16* dst = Qb + ((size_t)(b * 8 + h) * 1024 + l0) * 64 + d;
#pragma unroll
        for (int r = 0; r < 4; ++r) dst[(size_t)r * 64] = f2b(acc[i][j][r]);
      } else if (z == 1) {
        u16* dst = Kb + ((size_t)(b * 8 + h) * 1024 + l0) * 64 + d;
#pragma unroll
        for (int r = 0; r < 4; ++r) dst[(size_t)r * 64] = f2b(acc[i][j][r]);
      } else {
        vshort4 vs;
#pragma unroll
        for (int r = 0; r < 4; ++r)
          vs[r] = (short)(mask[b * 1024 + l0 + r] ? f2b(acc[i][j][r]) : (u16)0);
        *(vshort4*)(Vtb + ((size_t)(b * 8 + h) * 64 + d) * 1024 + l0) = vs;
      }
    }
  }
}

// ---- fused grid (R11 form): XCD-batch map, attn+G q-compaction; block 1536
//      computes gsums (reads R from the proj launch -> cross-launch safe).
__global__ __launch_bounds__(256) void attn_gv_k(
    const u16* __restrict__ Qb, const u16* __restrict__ Kb,
    const u16* __restrict__ Vtb, const u16* __restrict__ actb,
    const int* __restrict__ mask, const int* __restrict__ nvb,
    const int* __restrict__ itok, const float* __restrict__ R,
    u16* __restrict__ AEb, u16* __restrict__ AGb, float* __restrict__ denom) {
  __shared__ __align__(16) u16 POOL[13320];   // 26.6 KB
  const int t = threadIdx.x, w = t >> 6, lane = t & 63;
  const int l15 = lane & 15, quad = lane >> 4;

  if (blockIdx.x == 1536) {
    // ---- gsums: denom[8+b] = sum over valid q of R[q][b] ----
    float* rr = (float*)POOL;   // 4x8 floats
    float a8[8] = {0,0,0,0,0,0,0,0};
    for (int q = t; q < 1024; q += 256)
#pragma unroll
      for (int b = 0; b < 8; ++b)
        if (mask[b * 1024 + q]) a8[b] += R[q * 8 + b];
#pragma unroll
    for (int b = 0; b < 8; ++b) {
#pragma unroll
      for (int off = 32; off > 0; off >>= 1) a8[b] += __shfl_down(a8[b], off);
    }
    if (lane == 0)
#pragma unroll
      for (int b = 0; b < 8; ++b) rr[w * 8 + b] = a8[b];
    __syncthreads();
    if (t < 8) denom[8 + t] = rr[t] + rr[8 + t] + rr[16 + t] + rr[24 + t];
    return;
  }

  const int X = blockIdx.x & 7;      // XCD id (round-robin dispatch, m09)
  const int s = blockIdx.x >> 3;     // slot on this XCD [0,192)
  const int s3 = s % 3, sd3 = s / 3;

  if (s3 == 2) {
    // ---- G-path GEMM (compact q): AG[(X*1024+qc)][n] =
    //      sum_k act[tok(qc)][k] * Vtb[X*512+n][k]
    u16* As = POOL;           // 64 rows x 64 k  (8 KB)
    u16* Bs = POOL + 4096;    // 128 rows x 64 k (16 KB)
    const int b = X;
    const int q0 = (sd3 >> 2) * 64;          // 16 q-tiles
    const int n0 = (sd3 & 3) * 128;          // 4 n-tiles
    const int nv = nvb[b];
    if (q0 >= nv) return;                    // whole tile is discarded rows
    const int* it = itok + b * 1024;
    const int m0 = b * 1024 + q0;            // compact AGb row base
    const int mq = (w >> 1) * 32, nq = (w & 1) * 64;
    const ffrag fz = {0.f, 0.f, 0.f, 0.f};
    ffrag acc[2][4];
#pragma unroll
    for (int i = 0; i < 2; ++i)
#pragma unroll
      for (int j = 0; j < 4; ++j) acc[i][j] = fz;

    int tokr[2];
#pragma unroll
    for (int j = 0; j < 2; ++j) {
      const int c = w * 128 + j * 64 + lane;
      tokr[j] = it[q0 + (c >> 3)];
    }

    for (int kk = 0; kk < 1024; kk += 64) {
      __syncthreads();
#pragma unroll
      for (int j = 0; j < 2; ++j) {            // A: gathered valid rows
        const int c = w * 128 + j * 64 + lane;
        const int row = c >> 3, ck = (c & 7) ^ (row & 7);
        gll16(actb + (size_t)tokr[j] * 1024 + kk + ck * 8,
              &As[(size_t)(w * 128 + j * 64) * 8]);
      }
#pragma unroll
      for (int j = 0; j < 4; ++j) {            // B: 1024 16B chunks
        const int c = w * 256 + j * 64 + lane;
        const int row = c >> 3, ck = (c & 7) ^ (row & 7);
        gll16(Vtb + (size_t)(b * 512 + n0 + row) * 1024 + kk + ck * 8,
              &Bs[(size_t)(w * 256 + j * 64) * 8]);
      }
      __syncthreads();
#pragma unroll
      for (int sgm = 0; sgm < 2; ++sgm) {
        bfrag av[2], bv[4];
#pragma unroll
        for (int i = 0; i < 2; ++i) {
          const int ar = mq + i * 16 + l15;
          av[i] = *(const bfrag*)&As[ar * 64 + (((quad + 4 * sgm) ^ (ar & 7)) << 3)];
        }
#pragma unroll
        for (int j = 0; j < 4; ++j) {
          const int br = nq + j * 16 + l15;
          bv[j] = *(const bfrag*)&Bs[br * 64 + (((quad + 4 * sgm) ^ (br & 7)) << 3)];
        }
#pragma unroll
        for (int i = 0; i < 2; ++i)
#pragma unroll
          for (int j = 0; j < 4; ++j)
            acc[i][j] = __builtin_amdgcn_mfma_f32_16x16x32_bf16(av[i], bv[j], acc[i][j], 0, 0, 0);
      }
    }
#pragma unroll
    for (int i = 0; i < 2; ++i) {
      const int mbase = m0 + mq + i * 16 + quad * 4;     // compact row
#pragma unroll
      for (int j = 0; j < 4; ++j) {
        const int n = n0 + nq + j * 16 + l15;
#pragma unroll
        for (int r = 0; r < 4; ++r)
          AGb[(size_t)(mbase + r) * 512 + n] = f2b(acc[i][j][r]);
      }
    }
    return;
  }

  // ---- attention E-path: a = 2*sd3 + s3 in [0,128); compacted q space ----
  const int a_ = sd3 * 2 + s3;
  const int qt = a_ & 15;
  const int h = a_ >> 4;
  const int b = X;
  const int bh = X * 8 + h;
  const int nv = nvb[b];
  if (qt * 64 >= nv) return;          // tile entirely masked-q: no output used
  u16* Ks = POOL;             // 8 KB [k][d]
  u16* Vs = POOL + 4096;      // 8 KB [d][k]
  u16* Es = POOL + 8192;      // 8 KB [q][k]
  u16* Ms = POOL + 12288;     // 2 KB bf16 mask
  float* red4 = (float*)(POOL + 13312);
  const int l31 = lane & 31, hi = lane >> 5;
  const int qsb = w >> 1, msb = w & 1;   // S-phase: q-block, k(m)-block
  const int qpb = w & 1, dpb = w >> 1;   // PV-phase: q-block, d-block (distinct!)

  const u16* Kg = Kb + (size_t)bh * 65536;
  const u16* Vg = Vtb + (size_t)bh * 65536;

  const u16* Qrow = Qb + ((size_t)bh * 1024 + qt * 64 + qsb * 32 + l31) * 64;
  bfrag qf[4];
#pragma unroll
  for (int ko = 0; ko < 4; ++ko) qf[ko] = *(const bfrag*)(Qrow + ko * 16 + hi * 8);

  {
    int4 mi = *(const int4*)(mask + b * 1024 + t * 4);
    vshort4 mv;
    mv[0] = mi.x ? (short)0x3F80 : (short)0; mv[1] = mi.y ? (short)0x3F80 : (short)0;
    mv[2] = mi.z ? (short)0x3F80 : (short)0; mv[3] = mi.w ? (short)0x3F80 : (short)0;
    *(vshort4*)&Ms[t * 4] = mv;
  }

  auto stageK = [&](int kt) {
#pragma unroll
    for (int j = 0; j < 2; ++j) {
      const int c = w * 128 + j * 64 + lane;
      const int row = c >> 3, ck = (c & 7) ^ SWK(row);
      gll16(Kg + (size_t)(kt * 64 + row) * 64 + ck * 8,
            &Ks[(size_t)(w * 128 + j * 64) * 8]);
    }
  };
  auto stageV = [&](int kt) {
#pragma unroll
    for (int j = 0; j < 2; ++j) {
      const int c = w * 128 + j * 64 + lane;
      const int row = c >> 3, ck = (c & 7) ^ SWK(row);
      gll16(Vg + (size_t)row * 1024 + kt * 64 + ck * 8,
            &Vs[(size_t)(w * 128 + j * 64) * 8]);
    }
  };

  stageK(0); stageV(0);
  __syncthreads();

  ffrag16 accE, dacc;
#pragma unroll
  for (int i = 0; i < 16; ++i) { accE[i] = 0.f; dacc[i] = 0.f; }

  for (int kt = 0; kt < 16; ++kt) {
    // ---- S-phase: S^T block (m = wave's 32-k block, n = its 32-q block) ----
    ffrag16 st;
#pragma unroll
    for (int i = 0; i < 16; ++i) st[i] = 0.f;
    const int krow = msb * 32 + l31;
    const int kk7 = SWK(krow);
#pragma unroll
    for (int ko = 0; ko < 4; ++ko) {
      bfrag ak = *(const bfrag*)&Ks[krow * 64 + (((ko * 2 + hi) ^ kk7) << 3)];
      st = __builtin_amdgcn_mfma_f32_32x32x16_bf16(ak, qf[ko], st, 0, 0, 0);
    }
    // ---- nonlinearity -> Es (lane = q col; reg r -> k-local) ----
    const int qrow = qsb * 32 + l31;
    const int qk7 = SWK(qrow);
#pragma unroll
    for (int g = 0; g < 4; ++g) {
      float ee[4];
#pragma unroll
      for (int r = 0; r < 4; ++r) {
        const float tt = EXP2F(st[4 * g + r] * 0.360673760222f);
        ee[r] = EXP2F(RCPF(tt + 1.0f) * -2.88539008178f);
      }
      const int k0 = msb * 32 + g * 8 + hi * 4;
      *(uint2*)&Es[qrow * 64 + (((k0 >> 3) ^ qk7) << 3) + (k0 & 7)] =
          make_uint2(pk2(ee[0], ee[1]), pk2(ee[2], ee[3]));
    }
    __syncthreads();                   // Es visible; Ks reads done blockwide
    if (kt < 15) stageK(kt + 1);       // drains at next barrier

    // ---- PV: distinct quadrant per wave (E-path + denominator only) ----
    const int erow = qpb * 32 + l31;
    const int ek7 = SWK(erow);
    const int vrow = dpb * 32 + l31;
    const int vk7 = SWK(vrow);
#pragma unroll
    for (int ko = 0; ko < 4; ++ko) {
      const int co = ko * 2 + hi;
      bfrag ea = *(const bfrag*)&Es[erow * 64 + ((co ^ ek7) << 3)];
      bfrag bv = *(const bfrag*)&Vs[vrow * 64 + ((co ^ vk7) << 3)];
      accE = __builtin_amdgcn_mfma_f32_32x32x16_bf16(ea, bv, accE, 0, 0, 0);
      if (dpb == 0) {
        bfrag bm = *(const bfrag*)&Ms[kt * 64 + ko * 16 + hi * 8];
        dacc = __builtin_amdgcn_mfma_f32_32x32x16_bf16(ea, bm, dacc, 0, 0, 0);
      }
    }
    __syncthreads();                   // Vs/Es reads done; stageK drained
    if (kt < 15) stageV(kt + 1);
  }

  // ---- epilogue: wave stores its (qpb, dpb) quadrant of AE (compacted rows) -
  const size_t obase = ((size_t)(b * 1024 + qt * 64 + qpb * 32)) * 512
                       + h * 64 + dpb * 32 + l31;
#pragma unroll
  for (int r = 0; r < 16; ++r) {
    const int qloc = (r & 3) + 8 * (r >> 2) + 4 * hi;
    AEb[obase + (size_t)qloc * 512] = f2b(accE[r]);
  }
  // ---- denominator: q-filter is compact index < nv (valid-first order) ----
  float dsumv = 0.0f;
  if (l31 == 0 && dpb == 0) {
    const int cq0 = qt * 64 + qpb * 32 + 4 * hi;
#pragma unroll
    for (int r = 0; r < 16; ++r) {
      const int cq = cq0 + (r & 3) + 8 * (r >> 2);
      dsumv += (cq < nv) ? dacc[r] : 0.0f;
    }
    red4[qpb * 2 + hi] = dsumv;
  }
  __syncthreads();
  if (t == 0) atomicAdd(denom + b, red4[0] + red4[1] + red4[2] + red4[3]);
}

// ---- out = (mq*(c1*AE[pos] + c2*AG[pos])) @ Wo^T, 128x128 tiles -------------
__global__ __launch_bounds__(256) void o_proj_k(
    const u16* __restrict__ AEb, const u16* __restrict__ AGb,
    const int* __restrict__ mask, const int* __restrict__ posb,
    const float* __restrict__ sums,
    const u16* __restrict__ Wb, float* __restrict__ out) {
  const int m0 = blockIdx.x * 128;
  const int n0 = blockIdx.y * 128;
  const int b = m0 >> 10;
  const float c1 = 0.5f / fmaxf(sums[b], TINYF);
  const float c2 = 0.5f / fmaxf(sums[8 + b], TINYF);
  __shared__ __align__(16) u16 As[128 * 64];
  __shared__ __align__(16) u16 Bs[128 * 64];
  const int t = threadIdx.x, w = t >> 6, lane = t & 63;
  const int l15 = lane & 15, quad = lane >> 4;
  const int mq = (w >> 1) * 64, nq = (w & 1) * 64;
  int rowi[4], prw[4], mrow[4]; float c1r[4], c2r[4];
#pragma unroll
  for (int i = 0; i < 4; ++i) {
    const int c = t + i * 256;
    rowi[i] = c >> 3;
    const int tok = (m0 + rowi[i]) & 1023;
    mrow[i] = mask[b * 1024 + tok];
    prw[i] = posb[b * 1024 + tok];        // compacted row for this token
    c1r[i] = mrow[i] ? c1 : 0.0f;
    c2r[i] = mrow[i] ? c2 : 0.0f;
  }
  const ffrag fz = {0.f, 0.f, 0.f, 0.f};
  ffrag acc[4][4];
#pragma unroll
  for (int i = 0; i < 4; ++i)
#pragma unroll
    for (int j = 0; j < 4; ++j) acc[i][j] = fz;

  for (int kk = 0; kk < 512; kk += 64) {
    __syncthreads();
#pragma unroll
    for (int i = 0; i < 4; ++i) {
      const int c = t + i * 256;
      const int row = rowi[i], ck = c & 7;
      const size_t gofsE = (size_t)(b * 1024 + prw[i]) * 512 + kk + ck * 8;
      uint4 ua = *(const uint4*)(AEb + gofsE);
      uint4 ug = *(const uint4*)(AGb + gofsE);
      if (!mrow[i]) {                       // garbage rows: NaN-safe zero
        ua = make_uint4(0u, 0u, 0u, 0u);
        ug = make_uint4(0u, 0u, 0u, 0u);
      }
      const float a1 = c1r[i], a2 = c2r[i];
      uint4 res;
      res.x = pk2(a1 * blo(ua.x) + a2 * blo(ug.x), a1 * bhi(ua.x) + a2 * bhi(ug.x));
      res.y = pk2(a1 * blo(ua.y) + a2 * blo(ug.y), a1 * bhi(ua.y) + a2 * bhi(ug.y));
      res.z = pk2(a1 * blo(ua.z) + a2 * blo(ug.z), a1 * bhi(ua.z) + a2 * bhi(ug.z));
      res.w = pk2(a1 * blo(ua.w) + a2 * blo(ug.w), a1 * bhi(ua.w) + a2 * bhi(ug.w));
      *(uint4*)&As[row * 64 + ((ck ^ (row & 7)) << 3)] = res;
    }
#pragma unroll
    for (int j = 0; j < 4; ++j) {
      const int c = w * 256 + j * 64 + lane;
      const int row = c >> 3, ck = (c & 7) ^ (row & 7);
      gll16(Wb + (size_t)(1536 + n0 + row) * 512 + kk + ck * 8,
            &Bs[(size_t)(w * 256 + j * 64) * 8]);
    }
    __syncthreads();
#pragma unroll
    for (int s = 0; s < 2; ++s) {
      bfrag av[4], bv[4];
#pragma unroll
      for (int i = 0; i < 4; ++i) {
        const int ar = mq + i * 16 + l15;
        av[i] = *(const bfrag*)&As[ar * 64 + (((quad + 4 * s) ^ (ar & 7)) << 3)];
        const int br = nq + i * 16 + l15;
        bv[i] = *(const bfrag*)&Bs[br * 64 + (((quad + 4 * s) ^ (br & 7)) << 3)];
      }
#pragma unroll
      for (int i = 0; i < 4; ++i)
#pragma unroll
        for (int j = 0; j < 4; ++j)
          acc[i][j] = __builtin_amdgcn_mfma_f32_16x16x32_bf16(av[i], bv[j], acc[i][j], 0, 0, 0);
    }
  }
#pragma unroll
  for (int i = 0; i < 4; ++i) {
    const int mbase = m0 + mq + i * 16 + quad * 4;
#pragma unroll
    for (int j = 0; j < 4; ++j) {
      const int n = n0 + nq + j * 16 + l15;
#pragma unroll
      for (int r = 0; r < 4; ++r)
        out[(size_t)(mbase + r) * 512 + n] = acc[i][j][r];
    }
  }
}

extern "C" void kernel_launch(void* const* d_in, const int* in_sizes, int n_in,
                              void* d_out, int out_size, void* d_ws, size_t ws_size,
                              hipStream_t stream) {
  const float* x  = (const float*)d_in[0];
  const int* mask = (const int*)d_in[1];
  const float* Wq = (const float*)d_in[2];
  const float* Wk = (const float*)d_in[3];
  const float* Wv = (const float*)d_in[4];
  const float* Wo = (const float*)d_in[5];
  const float* G  = (const float*)d_in[6];
  float* out = (float*)d_out;

  u16* xb   = (u16*)d_ws;                    // 8192*512
  u16* Wb   = xb + (size_t)8192 * 512;       // 2048*512
  u16* Qb   = Wb + (size_t)2048 * 512;       // QSZ (compacted rows per batch)
  u16* Kb   = Qb + QSZ;                      // token space
  u16* Vtb  = Kb + QSZ;                      // token space
  u16* actb = Vtb + QSZ;                     // 1024*1024
  u16* AEb  = actb + (size_t)1024 * 1024;    // BLE (compacted rows per batch)
  u16* AGb  = AEb + BLE;                     // BLE (compacted rows per batch)
  float* R  = (float*)(AGb + BLE);           // 1024*8
  float* SUMS = R + 8192;                    // denom[8], gsums[8]
  int* posb = (int*)(SUMS + 16);             // 8*1024 token->compact position
  int* nvb  = posb + 8192;                   // 8 valid counts
  int* itok = nvb + 8;                       // 8*1024 compact->token (inverse)

  prep_k<<<2568, 256, 0, stream>>>(x, Wq, Wk, Wv, Wo, mask, xb, Wb, posb, nvb, itok, SUMS);
  proj_k<<<1792, 256, 0, stream>>>(xb, Wb, G, mask, nvb, itok, actb, R, Qb, Kb, Vtb);
  attn_gv_k<<<1537, 256, 0, stream>>>(Qb, Kb, Vtb, actb, mask, nvb, itok, R, AEb, AGb, SUMS);
  o_proj_k<<<dim3(64, 4), 256, 0, stream>>>(AEb, AGb, mask, posb, SUMS, Wb, out);
}

// Round 13
// 171.215 us; speedup vs baseline: 1.0660x; 1.0156x over previous
//
#include <hip/hip_runtime.h>
#include <math.h>

#define B_ 8
#define L_ 1024
#define E_ 512
#define H_ 8
#define D_ 64
#define QSZ (B_*H_*L_*D_)          // 4,194,304 elements
#define BLE ((size_t)B_*L_*E_)     // 4,194,304
#define TINYF 1.175494350822287508e-38f
#define SWK(r) ((((r) ^ ((r) >> 3))) & 7)   // full-entropy LDS chunk swizzle key

typedef unsigned short u16;
typedef __attribute__((ext_vector_type(8))) short bfrag;    // 8 bf16 (4 VGPRs)
typedef __attribute__((ext_vector_type(4))) float ffrag;    // 4 fp32 acc (16x16)
typedef __attribute__((ext_vector_type(16))) float ffrag16; // 16 fp32 acc (32x32)
typedef __attribute__((ext_vector_type(4))) short vshort4;

#if __has_builtin(__builtin_amdgcn_exp2f)
#define EXP2F(x) __builtin_amdgcn_exp2f(x)
#else
#define EXP2F(x) __expf((x) * 0.6931471805599453f)
#endif
#if __has_builtin(__builtin_amdgcn_rcpf)
#define RCPF(x) __builtin_amdgcn_rcpf(x)
#else
#define RCPF(x) (1.0f / (x))
#endif

__device__ __forceinline__ u16 f2b(float f) {
  unsigned u = __float_as_uint(f);
  u += 0x7fffu + ((u >> 16) & 1u);           // RNE
  return (u16)(u >> 16);
}
__device__ __forceinline__ unsigned pk2(float a, float b) {  // lo=rne(a), hi=rne(b)
  unsigned ua = __float_as_uint(a); ua += 0x7fffu + ((ua >> 16) & 1u);
  unsigned ub = __float_as_uint(b); ub += 0x7fffu + ((ub >> 16) & 1u);
  return (ua >> 16) | (ub & 0xffff0000u);
}
__device__ __forceinline__ float blo(unsigned u) { return __uint_as_float(u << 16); }
__device__ __forceinline__ float bhi(unsigned u) { return __uint_as_float(u & 0xffff0000u); }

__device__ __forceinline__ bfrag cvt8v(const float* __restrict__ src) {
  float4 a = *(const float4*)src;
  float4 b = *(const float4*)(src + 4);
  bfrag r;
  r[0]=(short)f2b(a.x); r[1]=(short)f2b(a.y); r[2]=(short)f2b(a.z); r[3]=(short)f2b(a.w);
  r[4]=(short)f2b(b.x); r[5]=(short)f2b(b.y); r[6]=(short)f2b(b.z); r[7]=(short)f2b(b.w);
  return r;
}

// async global->LDS, 16B per lane; lds base wave-uniform (HW adds lane*16);
// GLOBAL src addr is per-lane -> usable as a row-gather with linear LDS dest.
__device__ __forceinline__ void gll16(const void* g, void* l) {
  __builtin_amdgcn_global_load_lds(
      (const __attribute__((address_space(1))) void*)g,
      (__attribute__((address_space(3))) void*)l, 16, 0, 0);
}

// ---- prep: fp32->bf16 conversions + per-batch mask scan (+denom zero) -------
__global__ __launch_bounds__(256) void prep_k(
    const float* __restrict__ x, const float* __restrict__ Wq,
    const float* __restrict__ Wk, const float* __restrict__ Wv,
    const float* __restrict__ Wo, const int* __restrict__ mask,
    u16* __restrict__ xb, u16* __restrict__ Wb,
    int* __restrict__ posb, int* __restrict__ nvb, int* __restrict__ itok,
    float* __restrict__ sums) {
  const int bid = blockIdx.x, t = threadIdx.x;
  __shared__ int sc[256];
  if (bid < 2048) {
    size_t c = (size_t)bid * 256 + t;
    *(bfrag*)&xb[c * 8] = cvt8v(x + c * 8);
    return;
  }
  if (bid < 2560) {
    const int c2 = bid - 2048;
    const float* src = (c2 < 128) ? Wq : (c2 < 256) ? Wk : (c2 < 384) ? Wv : Wo;
    const size_t base = (size_t)(c2 >> 7) * 262144;
    const size_t cc = (size_t)(c2 & 127) * 256 + t;
    *(bfrag*)&Wb[base + cc * 8] = cvt8v(src + cc * 8);
    return;
  }
  // ---- per-batch valid-first permutation + inverse + denom zero ----
  const int bb = bid - 2560;
  int4 mi = *(const int4*)(mask + bb * 1024 + t * 4);
  const int vx = mi.x ? 1 : 0, vy = mi.y ? 1 : 0;
  const int vz = mi.z ? 1 : 0, vw = mi.w ? 1 : 0;
  const int c0 = vx + vy + vz + vw;
  sc[t] = c0;
  __syncthreads();
#pragma unroll
  for (int off = 1; off < 256; off <<= 1) {
    int v = (t >= off) ? sc[t - off] : 0;
    __syncthreads();
    sc[t] += v;
    __syncthreads();
  }
  const int nvtot = sc[255];
  int pv = sc[t] - c0;          // valid tokens before this thread's 4
  int pi = t * 4 - pv;          // invalid tokens before
  int4 pq;
  pq.x = vx ? pv : nvtot + pi; pv += vx; pi += 1 - vx;
  pq.y = vy ? pv : nvtot + pi; pv += vy; pi += 1 - vy;
  pq.z = vz ? pv : nvtot + pi; pv += vz; pi += 1 - vz;
  pq.w = vw ? pv : nvtot + pi;
  *(int4*)(posb + bb * 1024 + t * 4) = pq;
  itok[bb * 1024 + pq.x] = t * 4;
  itok[bb * 1024 + pq.y] = t * 4 + 1;
  itok[bb * 1024 + pq.z] = t * 4 + 2;
  itok[bb * 1024 + pq.w] = t * 4 + 3;
  if (t == 0) { nvb[bb] = nvtot; sums[bb] = 0.0f; }
}

// ---- fused launch 2: [0,1024) G-softmax blocks, [1024,1792) QKV GEMM --------
__global__ __launch_bounds__(256) void proj_k(
    const u16* __restrict__ xb, const u16* __restrict__ Wb,
    const float* __restrict__ G, const int* __restrict__ mask,
    const int* __restrict__ nvb, const int* __restrict__ itok,
    u16* __restrict__ actb, float* __restrict__ R,
    u16* __restrict__ Qb, u16* __restrict__ Kb, u16* __restrict__ Vtb) {
  const int bid = blockIdx.x, t = threadIdx.x;
  __shared__ __align__(16) u16 As[128 * 64];
  __shared__ __align__(16) u16 Bs[128 * 64];
  __shared__ float sred[8];
  __shared__ float rred[4][8];
  const int w = t >> 6, lane = t & 63;

  if (bid < 1024) {
    // ---- G-softmax (overlaps the latency-bound GEMM blocks, m114) ----
    const int q = bid;
    float4 g4 = ((const float4*)(G + (size_t)q * 1024))[t];
    float m = fmaxf(fmaxf(g4.x, g4.y), fmaxf(g4.z, g4.w));
#pragma unroll
    for (int off = 32; off > 0; off >>= 1) m = fmaxf(m, __shfl_down(m, off));
    if (lane == 0) sred[w] = m;
    __syncthreads();
    m = fmaxf(fmaxf(sred[0], sred[1]), fmaxf(sred[2], sred[3]));
    float e0 = __expf(g4.x - m), e1 = __expf(g4.y - m);
    float e2 = __expf(g4.z - m), e3 = __expf(g4.w - m);
    float s = e0 + e1 + e2 + e3;
#pragma unroll
    for (int off = 32; off > 0; off >>= 1) s += __shfl_down(s, off);
    if (lane == 0) sred[4 + w] = s;
    __syncthreads();
    const float inv = 1.0f / (sred[4] + sred[5] + sred[6] + sred[7]);
    const unsigned p0 = pk2(e0 * inv, e1 * inv);
    const unsigned p1 = pk2(e2 * inv, e3 * inv);
    *(uint2*)&actb[(size_t)q * 1024 + t * 4] = make_uint2(p0, p1);
    const float r0 = blo(p0), r1 = bhi(p0);
    const float r2 = blo(p1), r3 = bhi(p1);
    float rd[8];
#pragma unroll
    for (int b = 0; b < 8; ++b) {
      const int* mkp = mask + b * 1024 + t * 4;
      rd[b] = (mkp[0] ? r0 : 0.f) + (mkp[1] ? r1 : 0.f) +
              (mkp[2] ? r2 : 0.f) + (mkp[3] ? r3 : 0.f);
#pragma unroll
      for (int off = 32; off > 0; off >>= 1) rd[b] += __shfl_down(rd[b], off);
    }
    if (lane == 0)
#pragma unroll
      for (int b = 0; b < 8; ++b) rred[w][b] = rd[b];
    __syncthreads();
    if (t < 8) R[q * 8 + t] = rred[0][t] + rred[1][t] + rred[2][t] + rred[3][t];
    return;
  }

  // ---- QKV GEMM, 128x128 m97-shape tiles (gid = bid-1024, x fastest) ----
  const int gid = bid - 1024;
  const int m0 = (gid & 63) * 128;
  const int n0 = (gid >> 6) * 128;
  const int l15 = lane & 15, quad = lane >> 4;
  const int mq = (w >> 1) * 64, nq = (w & 1) * 64;
  const int z = n0 >> 9;          // 0=Q 1=K 2=V
  const int b = m0 >> 10, q0c = m0 & 1023;

  int tokr[4];
  if (z == 0) {
    const int nv = nvb[b];
    if (q0c >= nv) return;        // tile entirely discarded rows
    const int* it = itok + b * 1024;
#pragma unroll
    for (int j = 0; j < 4; ++j) {
      const int c = w * 256 + j * 64 + lane;
      tokr[j] = b * 1024 + it[q0c + (c >> 3)];
    }
  } else {
#pragma unroll
    for (int j = 0; j < 4; ++j) {
      const int c = w * 256 + j * 64 + lane;
      tokr[j] = m0 + (c >> 3);
    }
  }

  const ffrag fz = {0.f, 0.f, 0.f, 0.f};
  ffrag acc[4][4];
#pragma unroll
  for (int i = 0; i < 4; ++i)
#pragma unroll
    for (int j = 0; j < 4; ++j) acc[i][j] = fz;

  for (int kk = 0; kk < 512; kk += 64) {
    __syncthreads();
#pragma unroll
    for (int j = 0; j < 4; ++j) {
      const int c = w * 256 + j * 64 + lane;
      const int row = c >> 3, ck = (c & 7) ^ (row & 7);
      gll16(xb + (size_t)tokr[j] * 512 + kk + ck * 8,
            &As[(size_t)(w * 256 + j * 64) * 8]);
    }
#pragma unroll
    for (int j = 0; j < 4; ++j) {
      const int c = w * 256 + j * 64 + lane;
      const int row = c >> 3, ck = (c & 7) ^ (row & 7);
      gll16(Wb + (size_t)(n0 + row) * 512 + kk + ck * 8,
            &Bs[(size_t)(w * 256 + j * 64) * 8]);
    }
    __syncthreads();
#pragma unroll
    for (int s = 0; s < 2; ++s) {
      bfrag av[4], bv[4];
#pragma unroll
      for (int i = 0; i < 4; ++i) {
        const int ar = mq + i * 16 + l15;
        av[i] = *(const bfrag*)&As[ar * 64 + (((quad + 4 * s) ^ (ar & 7)) << 3)];
        const int br = nq + i * 16 + l15;
        bv[i] = *(const bfrag*)&Bs[br * 64 + (((quad + 4 * s) ^ (br & 7)) << 3)];
      }
#pragma unroll
      for (int i = 0; i < 4; ++i)
#pragma unroll
        for (int j = 0; j < 4; ++j)
          acc[i][j] = __builtin_amdgcn_mfma_f32_16x16x32_bf16(av[i], bv[j], acc[i][j], 0, 0, 0);
    }
  }
  const int c0 = n0 & 511;
#pragma unroll
  for (int i = 0; i < 4; ++i) {
    const int mbase = m0 + mq + i * 16 + quad * 4;
    const int l0 = mbase & 1023;         // compact row (z==0) / token (z>0)
#pragma unroll
    for (int j = 0; j < 4; ++j) {
      const int nc = c0 + nq + j * 16 + l15;
      const int h = nc >> 6, d = nc & 63;
      if (z == 0) {
        u16* dst = Qb + ((size_t)(b * 8 + h) * 1024 + l0) * 64 + d;
#pragma unroll
        for (int r = 0; r < 4; ++r) dst[(size_t)r * 64] = f2b(acc[i][j][r]);
      } else if (z == 1) {
        u16* dst = Kb + ((size_t)(b * 8 + h) * 1024 + l0) * 64 + d;
#pragma unroll
        for (int r = 0; r < 4; ++r) dst[(size_t)r * 64] = f2b(acc[i][j][r]);
      } else {
        vshort4 vs;
#pragma unroll
        for (int r = 0; r < 4; ++r)
          vs[r] = (short)(mask[b * 1024 + l0 + r] ? f2b(acc[i][j][r]) : (u16)0);
        *(vshort4*)(Vtb + ((size_t)(b * 8 + h) * 64 + d) * 1024 + l0) = vs;
      }
    }
  }
}

// ---- fused grid (R12 form): XCD-batch map, attn+G q-compaction; block 1536
//      computes gsums (reads R from the proj launch -> cross-launch safe).
__global__ __launch_bounds__(256) void attn_gv_k(
    const u16* __restrict__ Qb, const u16* __restrict__ Kb,
    const u16* __restrict__ Vtb, const u16* __restrict__ actb,
    const int* __restrict__ mask, const int* __restrict__ nvb,
    const int* __restrict__ itok, const float* __restrict__ R,
    u16* __restrict__ AEb, u16* __restrict__ AGb, float* __restrict__ denom) {
  __shared__ __align__(16) u16 POOL[13320];   // 26.6 KB
  const int t = threadIdx.x, w = t >> 6, lane = t & 63;
  const int l15 = lane & 15, quad = lane >> 4;

  if (blockIdx.x == 1536) {
    // ---- gsums: denom[8+b] = sum over valid q of R[q][b] ----
    float* rr = (float*)POOL;   // 4x8 floats
    float a8[8] = {0,0,0,0,0,0,0,0};
    for (int q = t; q < 1024; q += 256)
#pragma unroll
      for (int b = 0; b < 8; ++b)
        if (mask[b * 1024 + q]) a8[b] += R[q * 8 + b];
#pragma unroll
    for (int b = 0; b < 8; ++b) {
#pragma unroll
      for (int off = 32; off > 0; off >>= 1) a8[b] += __shfl_down(a8[b], off);
    }
    if (lane == 0)
#pragma unroll
      for (int b = 0; b < 8; ++b) rr[w * 8 + b] = a8[b];
    __syncthreads();
    if (t < 8) denom[8 + t] = rr[t] + rr[8 + t] + rr[16 + t] + rr[24 + t];
    return;
  }

  const int X = blockIdx.x & 7;      // XCD id (round-robin dispatch, m09)
  const int s = blockIdx.x >> 3;     // slot on this XCD [0,192)
  const int s3 = s % 3, sd3 = s / 3;

  if (s3 == 2) {
    // ---- G-path GEMM (compact q): AG[(X*1024+qc)][n] =
    //      sum_k act[tok(qc)][k] * Vtb[X*512+n][k]
    u16* As = POOL;           // 64 rows x 64 k  (8 KB)
    u16* Bs = POOL + 4096;    // 128 rows x 64 k (16 KB)
    const int b = X;
    const int q0 = (sd3 >> 2) * 64;          // 16 q-tiles
    const int n0 = (sd3 & 3) * 128;          // 4 n-tiles
    const int nv = nvb[b];
    if (q0 >= nv) return;                    // whole tile is discarded rows
    const int* it = itok + b * 1024;
    const int m0 = b * 1024 + q0;            // compact AGb row base
    const int mq = (w >> 1) * 32, nq = (w & 1) * 64;
    const ffrag fz = {0.f, 0.f, 0.f, 0.f};
    ffrag acc[2][4];
#pragma unroll
    for (int i = 0; i < 2; ++i)
#pragma unroll
      for (int j = 0; j < 4; ++j) acc[i][j] = fz;

    int tokr[2];
#pragma unroll
    for (int j = 0; j < 2; ++j) {
      const int c = w * 128 + j * 64 + lane;
      tokr[j] = it[q0 + (c >> 3)];
    }

    for (int kk = 0; kk < 1024; kk += 64) {
      __syncthreads();
#pragma unroll
      for (int j = 0; j < 2; ++j) {            // A: gathered valid rows
        const int c = w * 128 + j * 64 + lane;
        const int row = c >> 3, ck = (c & 7) ^ (row & 7);
        gll16(actb + (size_t)tokr[j] * 1024 + kk + ck * 8,
              &As[(size_t)(w * 128 + j * 64) * 8]);
      }
#pragma unroll
      for (int j = 0; j < 4; ++j) {            // B: 1024 16B chunks
        const int c = w * 256 + j * 64 + lane;
        const int row = c >> 3, ck = (c & 7) ^ (row & 7);
        gll16(Vtb + (size_t)(b * 512 + n0 + row) * 1024 + kk + ck * 8,
              &Bs[(size_t)(w * 256 + j * 64) * 8]);
      }
      __syncthreads();
#pragma unroll
      for (int sgm = 0; sgm < 2; ++sgm) {
        bfrag av[2], bv[4];
#pragma unroll
        for (int i = 0; i < 2; ++i) {
          const int ar = mq + i * 16 + l15;
          av[i] = *(const bfrag*)&As[ar * 64 + (((quad + 4 * sgm) ^ (ar & 7)) << 3)];
        }
#pragma unroll
        for (int j = 0; j < 4; ++j) {
          const int br = nq + j * 16 + l15;
          bv[j] = *(const bfrag*)&Bs[br * 64 + (((quad + 4 * sgm) ^ (br & 7)) << 3)];
        }
#pragma unroll
        for (int i = 0; i < 2; ++i)
#pragma unroll
          for (int j = 0; j < 4; ++j)
            acc[i][j] = __builtin_amdgcn_mfma_f32_16x16x32_bf16(av[i], bv[j], acc[i][j], 0, 0, 0);
      }
    }
#pragma unroll
    for (int i = 0; i < 2; ++i) {
      const int mbase = m0 + mq + i * 16 + quad * 4;     // compact row
#pragma unroll
      for (int j = 0; j < 4; ++j) {
        const int n = n0 + nq + j * 16 + l15;
#pragma unroll
        for (int r = 0; r < 4; ++r)
          AGb[(size_t)(mbase + r) * 512 + n] = f2b(acc[i][j][r]);
      }
    }
    return;
  }

  // ---- attention E-path: a = 2*sd3 + s3 in [0,128); compacted q space ----
  const int a_ = sd3 * 2 + s3;
  const int qt = a_ & 15;
  const int h = a_ >> 4;
  const int b = X;
  const int bh = X * 8 + h;
  const int nv = nvb[b];
  if (qt * 64 >= nv) return;          // tile entirely masked-q: no output used
  u16* Ks = POOL;             // 8 KB [k][d]
  u16* Vs = POOL + 4096;      // 8 KB [d][k]
  u16* Es = POOL + 8192;      // 8 KB [q][k]
  u16* Ms = POOL + 12288;     // 2 KB bf16 mask
  float* red4 = (float*)(POOL + 13312);
  const int l31 = lane & 31, hi = lane >> 5;
  const int qsb = w >> 1, msb = w & 1;   // S-phase: q-block, k(m)-block
  const int qpb = w & 1, dpb = w >> 1;   // PV-phase: q-block, d-block (distinct!)

  const u16* Kg = Kb + (size_t)bh * 65536;
  const u16* Vg = Vtb + (size_t)bh * 65536;

  const u16* Qrow = Qb + ((size_t)bh * 1024 + qt * 64 + qsb * 32 + l31) * 64;
  bfrag qf[4];
#pragma unroll
  for (int ko = 0; ko < 4; ++ko) qf[ko] = *(const bfrag*)(Qrow + ko * 16 + hi * 8);

  {
    int4 mi = *(const int4*)(mask + b * 1024 + t * 4);
    vshort4 mv;
    mv[0] = mi.x ? (short)0x3F80 : (short)0; mv[1] = mi.y ? (short)0x3F80 : (short)0;
    mv[2] = mi.z ? (short)0x3F80 : (short)0; mv[3] = mi.w ? (short)0x3F80 : (short)0;
    *(vshort4*)&Ms[t * 4] = mv;
  }

  auto stageK = [&](int kt) {
#pragma unroll
    for (int j = 0; j < 2; ++j) {
      const int c = w * 128 + j * 64 + lane;
      const int row = c >> 3, ck = (c & 7) ^ SWK(row);
      gll16(Kg + (size_t)(kt * 64 + row) * 64 + ck * 8,
            &Ks[(size_t)(w * 128 + j * 64) * 8]);
    }
  };
  auto stageV = [&](int kt) {
#pragma unroll
    for (int j = 0; j < 2; ++j) {
      const int c = w * 128 + j * 64 + lane;
      const int row = c >> 3, ck = (c & 7) ^ SWK(row);
      gll16(Vg + (size_t)row * 1024 + kt * 64 + ck * 8,
            &Vs[(size_t)(w * 128 + j * 64) * 8]);
    }
  };

  stageK(0); stageV(0);
  __syncthreads();

  ffrag16 accE, dacc;
#pragma unroll
  for (int i = 0; i < 16; ++i) { accE[i] = 0.f; dacc[i] = 0.f; }

  for (int kt = 0; kt < 16; ++kt) {
    // ---- S-phase: S^T block (m = wave's 32-k block, n = its 32-q block) ----
    ffrag16 st;
#pragma unroll
    for (int i = 0; i < 16; ++i) st[i] = 0.f;
    const int krow = msb * 32 + l31;
    const int kk7 = SWK(krow);
#pragma unroll
    for (int ko = 0; ko < 4; ++ko) {
      bfrag ak = *(const bfrag*)&Ks[krow * 64 + (((ko * 2 + hi) ^ kk7) << 3)];
      st = __builtin_amdgcn_mfma_f32_32x32x16_bf16(ak, qf[ko], st, 0, 0, 0);
    }
    // ---- nonlinearity -> Es (lane = q col; reg r -> k-local) ----
    const int qrow = qsb * 32 + l31;
    const int qk7 = SWK(qrow);
#pragma unroll
    for (int g = 0; g < 4; ++g) {
      float ee[4];
#pragma unroll
      for (int r = 0; r < 4; ++r) {
        const float tt = EXP2F(st[4 * g + r] * 0.360673760222f);
        ee[r] = EXP2F(RCPF(tt + 1.0f) * -2.88539008178f);
      }
      const int k0 = msb * 32 + g * 8 + hi * 4;
      *(uint2*)&Es[qrow * 64 + (((k0 >> 3) ^ qk7) << 3) + (k0 & 7)] =
          make_uint2(pk2(ee[0], ee[1]), pk2(ee[2], ee[3]));
    }
    __syncthreads();                   // Es visible; Ks reads done blockwide
    if (kt < 15) stageK(kt + 1);       // drains at next barrier

    // ---- PV: distinct quadrant per wave (E-path + denominator only) ----
    const int erow = qpb * 32 + l31;
    const int ek7 = SWK(erow);
    const int vrow = dpb * 32 + l31;
    const int vk7 = SWK(vrow);
#pragma unroll
    for (int ko = 0; ko < 4; ++ko) {
      const int co = ko * 2 + hi;
      bfrag ea = *(const bfrag*)&Es[erow * 64 + ((co ^ ek7) << 3)];
      bfrag bv = *(const bfrag*)&Vs[vrow * 64 + ((co ^ vk7) << 3)];
      accE = __builtin_amdgcn_mfma_f32_32x32x16_bf16(ea, bv, accE, 0, 0, 0);
      if (dpb == 0) {
        bfrag bm = *(const bfrag*)&Ms[kt * 64 + ko * 16 + hi * 8];
        dacc = __builtin_amdgcn_mfma_f32_32x32x16_bf16(ea, bm, dacc, 0, 0, 0);
      }
    }
    __syncthreads();                   // Vs/Es reads done; stageK drained
    if (kt < 15) stageV(kt + 1);
  }

  // ---- epilogue: wave stores its (qpb, dpb) quadrant of AE (compacted rows) -
  const size_t obase = ((size_t)(b * 1024 + qt * 64 + qpb * 32)) * 512
                       + h * 64 + dpb * 32 + l31;
#pragma unroll
  for (int r = 0; r < 16; ++r) {
    const int qloc = (r & 3) + 8 * (r >> 2) + 4 * hi;
    AEb[obase + (size_t)qloc * 512] = f2b(accE[r]);
  }
  // ---- denominator: q-filter is compact index < nv (valid-first order) ----
  float dsumv = 0.0f;
  if (l31 == 0 && dpb == 0) {
    const int cq0 = qt * 64 + qpb * 32 + 4 * hi;
#pragma unroll
    for (int r = 0; r < 16; ++r) {
      const int cq = cq0 + (r & 3) + 8 * (r >> 2);
      dsumv += (cq < nv) ? dacc[r] : 0.0f;
    }
    red4[qpb * 2 + hi] = dsumv;
  }
  __syncthreads();
  if (t == 0) atomicAdd(denom + b, red4[0] + red4[1] + red4[2] + red4[3]);
}

// ---- out = (c1*AE + c2*AG) @ Wo^T in COMPACT row space, scatter via itok ----
// R13: AE/AG are already compact -> tile over compact rows (contiguous loads,
// prw/mask gathers deleted). Tiles past nv skip the GEMM and zero-fill their
// token rows; partial tiles zero rows >= nv in the epilogue. Valid-row bits
// identical (same c1*AE+c2*AG inputs, same MFMA order); invalid rows were
// exact 0.0f before too. ~47% of GEMM work removed (R7/R11/R12 mechanism).
__global__ __launch_bounds__(256) void o_proj_k(
    const u16* __restrict__ AEb, const u16* __restrict__ AGb,
    const int* __restrict__ nvb, const int* __restrict__ itok,
    const float* __restrict__ sums,
    const u16* __restrict__ Wb, float* __restrict__ out) {
  const int m0 = blockIdx.x * 128;      // compact row space
  const int n0 = blockIdx.y * 128;
  const int b = m0 >> 10;
  const int q0c = m0 & 1023;
  const int nv = nvb[b];
  const int* it = itok + b * 1024;
  const int t = threadIdx.x, w = t >> 6, lane = t & 63;

  if (q0c >= nv) {
    // ---- all-invalid tile: zero-fill out[token rows][n0..n0+128) ----
    const int row = q0c + (t >> 1);
    const int tok = it[row];
    float4 z4 = make_float4(0.f, 0.f, 0.f, 0.f);
    float* dst = out + ((size_t)(b * 1024 + tok)) * 512 + n0 + (t & 1) * 64;
#pragma unroll
    for (int i = 0; i < 16; ++i) *(float4*)(dst + i * 4) = z4;
    return;
  }

  const float c1 = 0.5f / fmaxf(sums[b], TINYF);
  const float c2 = 0.5f / fmaxf(sums[8 + b], TINYF);
  __shared__ __align__(16) u16 As[128 * 64];
  __shared__ __align__(16) u16 Bs[128 * 64];
  const int l15 = lane & 15, quad = lane >> 4;
  const int mq = (w >> 1) * 64, nq = (w & 1) * 64;

  const ffrag fz = {0.f, 0.f, 0.f, 0.f};
  ffrag acc[4][4];
#pragma unroll
  for (int i = 0; i < 4; ++i)
#pragma unroll
    for (int j = 0; j < 4; ++j) acc[i][j] = fz;

  for (int kk = 0; kk < 512; kk += 64) {
    __syncthreads();
#pragma unroll
    for (int i = 0; i < 4; ++i) {
      const int c = t + i * 256;
      const int row = c >> 3, ck = c & 7;
      const size_t gofs = (size_t)(b * 1024 + q0c + row) * 512 + kk + ck * 8;
      uint4 ua = *(const uint4*)(AEb + gofs);
      uint4 ug = *(const uint4*)(AGb + gofs);
      const int valid = (q0c + row) < nv;
      const float a1 = valid ? c1 : 0.0f, a2 = valid ? c2 : 0.0f;
      uint4 res;
      res.x = pk2(a1 * blo(ua.x) + a2 * blo(ug.x), a1 * bhi(ua.x) + a2 * bhi(ug.x));
      res.y = pk2(a1 * blo(ua.y) + a2 * blo(ug.y), a1 * bhi(ua.y) + a2 * bhi(ug.y));
      res.z = pk2(a1 * blo(ua.z) + a2 * blo(ug.z), a1 * bhi(ua.z) + a2 * bhi(ug.z));
      res.w = pk2(a1 * blo(ua.w) + a2 * blo(ug.w), a1 * bhi(ua.w) + a2 * bhi(ug.w));
      *(uint4*)&As[row * 64 + ((ck ^ (row & 7)) << 3)] = res;
    }
#pragma unroll
    for (int j = 0; j < 4; ++j) {
      const int c = w * 256 + j * 64 + lane;
      const int row = c >> 3, ck = (c & 7) ^ (row & 7);
      gll16(Wb + (size_t)(1536 + n0 + row) * 512 + kk + ck * 8,
            &Bs[(size_t)(w * 256 + j * 64) * 8]);
    }
    __syncthreads();
#pragma unroll
    for (int s = 0; s < 2; ++s) {
      bfrag av[4], bv[4];
#pragma unroll
      for (int i = 0; i < 4; ++i) {
        const int ar = mq + i * 16 + l15;
        av[i] = *(const bfrag*)&As[ar * 64 + (((quad + 4 * s) ^ (ar & 7)) << 3)];
        const int br = nq + i * 16 + l15;
        bv[i] = *(const bfrag*)&Bs[br * 64 + (((quad + 4 * s) ^ (br & 7)) << 3)];
      }
#pragma unroll
      for (int i = 0; i < 4; ++i)
#pragma unroll
        for (int j = 0; j < 4; ++j)
          acc[i][j] = __builtin_amdgcn_mfma_f32_16x16x32_bf16(av[i], bv[j], acc[i][j], 0, 0, 0);
    }
  }
  // ---- epilogue: scatter rows to token positions (row-granular) ----
#pragma unroll
  for (int i = 0; i < 4; ++i) {
    const int crow0 = q0c + mq + i * 16 + quad * 4;      // %4 == 0
    const int4 tk = *(const int4*)(it + crow0);
#pragma unroll
    for (int j = 0; j < 4; ++j) {
      const int n = n0 + nq + j * 16 + l15;
      out[(size_t)(b * 1024 + tk.x) * 512 + n] = (crow0     < nv) ? acc[i][j][0] : 0.0f;
      out[(size_t)(b * 1024 + tk.y) * 512 + n] = (crow0 + 1 < nv) ? acc[i][j][1] : 0.0f;
      out[(size_t)(b * 1024 + tk.z) * 512 + n] = (crow0 + 2 < nv) ? acc[i][j][2] : 0.0f;
      out[(size_t)(b * 1024 + tk.w) * 512 + n] = (crow0 + 3 < nv) ? acc[i][j][3] : 0.0f;
    }
  }
}

extern "C" void kernel_launch(void* const* d_in, const int* in_sizes, int n_in,
                              void* d_out, int out_size, void* d_ws, size_t ws_size,
                              hipStream_t stream) {
  const float* x  = (const float*)d_in[0];
  const int* mask = (const int*)d_in[1];
  const float* Wq = (const float*)d_in[2];
  const float* Wk = (const float*)d_in[3];
  const float* Wv = (const float*)d_in[4];
  const float* Wo = (const float*)d_in[5];
  const float* G  = (const float*)d_in[6];
  float* out = (float*)d_out;

  u16* xb   = (u16*)d_ws;                    // 8192*512
  u16* Wb   = xb + (size_t)8192 * 512;       // 2048*512
  u16* Qb   = Wb + (size_t)2048 * 512;       // QSZ (compacted rows per batch)
  u16* Kb   = Qb + QSZ;                      // token space
  u16* Vtb  = Kb + QSZ;                      // token space
  u16* actb = Vtb + QSZ;                     // 1024*1024
  u16* AEb  = actb + (size_t)1024 * 1024;    // BLE (compacted rows per batch)
  u16* AGb  = AEb + BLE;                     // BLE (compacted rows per batch)
  float* R  = (float*)(AGb + BLE);           // 1024*8
  float* SUMS = R + 8192;                    // denom[8], gsums[8]
  int* posb = (int*)(SUMS + 16);             // 8*1024 token->compact position
  int* nvb  = posb + 8192;                   // 8 valid counts
  int* itok = nvb + 8;                       // 8*1024 compact->token (inverse)

  prep_k<<<2568, 256, 0, stream>>>(x, Wq, Wk, Wv, Wo, mask, xb, Wb, posb, nvb, itok, SUMS);
  proj_k<<<1792, 256, 0, stream>>>(xb, Wb, G, mask, nvb, itok, actb, R, Qb, Kb, Vtb);
  attn_gv_k<<<1537, 256, 0, stream>>>(Qb, Kb, Vtb, actb, mask, nvb, itok, R, AEb, AGb, SUMS);
  o_proj_k<<<dim3(64, 4), 256, 0, stream>>>(AEb, AGb, nvb, itok, SUMS, Wb, out);
}

// Round 14
// 159.186 us; speedup vs baseline: 1.1465x; 1.0756x over previous
//
#include <hip/hip_runtime.h>
#include <math.h>

#define B_ 8
#define L_ 1024
#define E_ 512
#define H_ 8
#define D_ 64
#define QSZ (B_*H_*L_*D_)          // 4,194,304 elements
#define BLE ((size_t)B_*L_*E_)     // 4,194,304
#define TINYF 1.175494350822287508e-38f
#define SWK(r) ((((r) ^ ((r) >> 3))) & 7)   // full-entropy LDS chunk swizzle key

typedef unsigned short u16;
typedef __attribute__((ext_vector_type(8))) short bfrag;    // 8 bf16 (4 VGPRs)
typedef __attribute__((ext_vector_type(4))) float ffrag;    // 4 fp32 acc (16x16)
typedef __attribute__((ext_vector_type(16))) float ffrag16; // 16 fp32 acc (32x32)
typedef __attribute__((ext_vector_type(4))) short vshort4;

#if __has_builtin(__builtin_amdgcn_exp2f)
#define EXP2F(x) __builtin_amdgcn_exp2f(x)
#else
#define EXP2F(x) __expf((x) * 0.6931471805599453f)
#endif
#if __has_builtin(__builtin_amdgcn_rcpf)
#define RCPF(x) __builtin_amdgcn_rcpf(x)
#else
#define RCPF(x) (1.0f / (x))
#endif

__device__ __forceinline__ u16 f2b(float f) {
  unsigned u = __float_as_uint(f);
  u += 0x7fffu + ((u >> 16) & 1u);           // RNE
  return (u16)(u >> 16);
}
__device__ __forceinline__ unsigned pk2(float a, float b) {  // lo=rne(a), hi=rne(b)
  unsigned ua = __float_as_uint(a); ua += 0x7fffu + ((ua >> 16) & 1u);
  unsigned ub = __float_as_uint(b); ub += 0x7fffu + ((ub >> 16) & 1u);
  return (ua >> 16) | (ub & 0xffff0000u);
}
__device__ __forceinline__ float blo(unsigned u) { return __uint_as_float(u << 16); }
__device__ __forceinline__ float bhi(unsigned u) { return __uint_as_float(u & 0xffff0000u); }
__device__ __forceinline__ float b2f(u16 v) { return __uint_as_float((unsigned)v << 16); }

__device__ __forceinline__ bfrag cvt8v(const float* __restrict__ src) {
  float4 a = *(const float4*)src;
  float4 b = *(const float4*)(src + 4);
  bfrag r;
  r[0]=(short)f2b(a.x); r[1]=(short)f2b(a.y); r[2]=(short)f2b(a.z); r[3]=(short)f2b(a.w);
  r[4]=(short)f2b(b.x); r[5]=(short)f2b(b.y); r[6]=(short)f2b(b.z); r[7]=(short)f2b(b.w);
  return r;
}

// async global->LDS, 16B per lane; lds base wave-uniform (HW adds lane*16);
// GLOBAL src addr is per-lane -> usable as a row-gather with linear LDS dest.
__device__ __forceinline__ void gll16(const void* g, void* l) {
  __builtin_amdgcn_global_load_lds(
      (const __attribute__((address_space(1))) void*)g,
      (__attribute__((address_space(3))) void*)l, 16, 0, 0);
}

// ---- prep: fp32->bf16 conversions + per-batch mask scan (+denom zero) -------
__global__ __launch_bounds__(256) void prep_k(
    const float* __restrict__ x, const float* __restrict__ Wq,
    const float* __restrict__ Wk, const float* __restrict__ Wv,
    const float* __restrict__ Wo, const int* __restrict__ mask,
    u16* __restrict__ xb, u16* __restrict__ Wb,
    int* __restrict__ posb, int* __restrict__ nvb, int* __restrict__ itok,
    float* __restrict__ sums) {
  const int bid = blockIdx.x, t = threadIdx.x;
  __shared__ int sc[256];
  if (bid < 2048) {
    size_t c = (size_t)bid * 256 + t;
    *(bfrag*)&xb[c * 8] = cvt8v(x + c * 8);
    return;
  }
  if (bid < 2560) {
    const int c2 = bid - 2048;
    const float* src = (c2 < 128) ? Wq : (c2 < 256) ? Wk : (c2 < 384) ? Wv : Wo;
    const size_t base = (size_t)(c2 >> 7) * 262144;
    const size_t cc = (size_t)(c2 & 127) * 256 + t;
    *(bfrag*)&Wb[base + cc * 8] = cvt8v(src + cc * 8);
    return;
  }
  // ---- per-batch valid-first permutation + inverse + denom zero ----
  const int bb = bid - 2560;
  int4 mi = *(const int4*)(mask + bb * 1024 + t * 4);
  const int vx = mi.x ? 1 : 0, vy = mi.y ? 1 : 0;
  const int vz = mi.z ? 1 : 0, vw = mi.w ? 1 : 0;
  const int c0 = vx + vy + vz + vw;
  sc[t] = c0;
  __syncthreads();
#pragma unroll
  for (int off = 1; off < 256; off <<= 1) {
    int v = (t >= off) ? sc[t - off] : 0;
    __syncthreads();
    sc[t] += v;
    __syncthreads();
  }
  const int nvtot = sc[255];
  int pv = sc[t] - c0;          // valid tokens before this thread's 4
  int pi = t * 4 - pv;          // invalid tokens before
  int4 pq;
  pq.x = vx ? pv : nvtot + pi; pv += vx; pi += 1 - vx;
  pq.y = vy ? pv : nvtot + pi; pv += vy; pi += 1 - vy;
  pq.z = vz ? pv : nvtot + pi; pv += vz; pi += 1 - vz;
  pq.w = vw ? pv : nvtot + pi;
  *(int4*)(posb + bb * 1024 + t * 4) = pq;
  itok[bb * 1024 + pq.x] = t * 4;
  itok[bb * 1024 + pq.y] = t * 4 + 1;
  itok[bb * 1024 + pq.z] = t * 4 + 2;
  itok[bb * 1024 + pq.w] = t * 4 + 3;
  if (t == 0) { nvb[bb] = nvtot; sums[bb] = 0.0f; }
}

// ---- fused launch 2: [0,1024) G-softmax blocks, [1024,1792) QKV GEMM --------
// R14 FULL k-COMPACTION via input gathers (no scatter anywhere):
//  - Q/K/V blocks ALL gather valid x rows via itok (per-lane gll16 src),
//    exit past nv, write CONTIGUOUS compact rows. V zero-predicate = row>=nv
//    (zeros land inside the partial tile since r64<=r128).
//  - softmax blocks write per-batch column-compacted act: actc[b][pos_q][pos_k]
//    = act (valid) or 0 (invalid). pos is a permutation -> every row+col
//    written, no garbage. Replaces actb (G-GEMM was its only consumer).
__global__ __launch_bounds__(256) void proj_k(
    const u16* __restrict__ xb, const u16* __restrict__ Wb,
    const float* __restrict__ G, const int* __restrict__ mask,
    const int* __restrict__ posb, const int* __restrict__ nvb,
    const int* __restrict__ itok,
    u16* __restrict__ actc, float* __restrict__ R,
    u16* __restrict__ Qb, u16* __restrict__ Kb, u16* __restrict__ Vtb) {
  const int bid = blockIdx.x, t = threadIdx.x;
  __shared__ __align__(16) u16 As[128 * 64];
  __shared__ __align__(16) u16 Bs[128 * 64];
  __shared__ float sred[8];
  __shared__ float rred[4][8];
  const int w = t >> 6, lane = t & 63;

  if (bid < 1024) {
    // ---- G-softmax -> per-batch compacted act (overlaps GEMM, m114) ----
    const int q = bid;
    float4 g4 = ((const float4*)(G + (size_t)q * 1024))[t];
    float m = fmaxf(fmaxf(g4.x, g4.y), fmaxf(g4.z, g4.w));
#pragma unroll
    for (int off = 32; off > 0; off >>= 1) m = fmaxf(m, __shfl_down(m, off));
    if (lane == 0) sred[w] = m;
    __syncthreads();
    m = fmaxf(fmaxf(sred[0], sred[1]), fmaxf(sred[2], sred[3]));
    float e0 = __expf(g4.x - m), e1 = __expf(g4.y - m);
    float e2 = __expf(g4.z - m), e3 = __expf(g4.w - m);
    float s = e0 + e1 + e2 + e3;
#pragma unroll
    for (int off = 32; off > 0; off >>= 1) s += __shfl_down(s, off);
    if (lane == 0) sred[4 + w] = s;
    __syncthreads();
    const float inv = 1.0f / (sred[4] + sred[5] + sred[6] + sred[7]);
    const u16 a0 = f2b(e0 * inv), a1 = f2b(e1 * inv);
    const u16 a2 = f2b(e2 * inv), a3 = f2b(e3 * inv);
    const float r0 = b2f(a0), r1 = b2f(a1), r2 = b2f(a2), r3 = b2f(a3);
    float rd[8];
#pragma unroll
    for (int b = 0; b < 8; ++b) {
      const int4 mi = *(const int4*)(mask + b * 1024 + t * 4);
      const int4 pk = *(const int4*)(posb + b * 1024 + t * 4);
      const int rowc = posb[b * 1024 + q];           // this G-row's compact pos
      u16* dst = actc + ((size_t)b << 20) + ((size_t)rowc << 10);
      dst[pk.x] = mi.x ? a0 : (u16)0;
      dst[pk.y] = mi.y ? a1 : (u16)0;
      dst[pk.z] = mi.z ? a2 : (u16)0;
      dst[pk.w] = mi.w ? a3 : (u16)0;
      rd[b] = (mi.x ? r0 : 0.f) + (mi.y ? r1 : 0.f) +
              (mi.z ? r2 : 0.f) + (mi.w ? r3 : 0.f);
#pragma unroll
      for (int off = 32; off > 0; off >>= 1) rd[b] += __shfl_down(rd[b], off);
    }
    if (lane == 0)
#pragma unroll
      for (int b = 0; b < 8; ++b) rred[w][b] = rd[b];
    __syncthreads();
    if (t < 8) R[q * 8 + t] = rred[0][t] + rred[1][t] + rred[2][t] + rred[3][t];
    return;
  }

  // ---- QKV GEMM, 128x128 m97-shape tiles (gid = bid-1024, x fastest) ----
  const int gid = bid - 1024;
  const int m0 = (gid & 63) * 128;
  const int n0 = (gid >> 6) * 128;
  const int l15 = lane & 15, quad = lane >> 4;
  const int mq = (w >> 1) * 64, nq = (w & 1) * 64;
  const int z = n0 >> 9;          // 0=Q 1=K 2=V
  const int b = m0 >> 10, q0c = m0 & 1023;
  const int nv = nvb[b];
  if (q0c >= nv) return;          // all of Q/K/V: rows past nv never consumed
  const int* it = itok + b * 1024;
  int tokr[4];
#pragma unroll
  for (int j = 0; j < 4; ++j) {
    const int c = w * 256 + j * 64 + lane;
    tokr[j] = b * 1024 + it[q0c + (c >> 3)];
  }

  const ffrag fz = {0.f, 0.f, 0.f, 0.f};
  ffrag acc[4][4];
#pragma unroll
  for (int i = 0; i < 4; ++i)
#pragma unroll
    for (int j = 0; j < 4; ++j) acc[i][j] = fz;

  for (int kk = 0; kk < 512; kk += 64) {
    __syncthreads();
#pragma unroll
    for (int j = 0; j < 4; ++j) {
      const int c = w * 256 + j * 64 + lane;
      const int row = c >> 3, ck = (c & 7) ^ (row & 7);
      gll16(xb + (size_t)tokr[j] * 512 + kk + ck * 8,
            &As[(size_t)(w * 256 + j * 64) * 8]);
    }
#pragma unroll
    for (int j = 0; j < 4; ++j) {
      const int c = w * 256 + j * 64 + lane;
      const int row = c >> 3, ck = (c & 7) ^ (row & 7);
      gll16(Wb + (size_t)(n0 + row) * 512 + kk + ck * 8,
            &Bs[(size_t)(w * 256 + j * 64) * 8]);
    }
    __syncthreads();
#pragma unroll
    for (int s = 0; s < 2; ++s) {
      bfrag av[4], bv[4];
#pragma unroll
      for (int i = 0; i < 4; ++i) {
        const int ar = mq + i * 16 + l15;
        av[i] = *(const bfrag*)&As[ar * 64 + (((quad + 4 * s) ^ (ar & 7)) << 3)];
        const int br = nq + i * 16 + l15;
        bv[i] = *(const bfrag*)&Bs[br * 64 + (((quad + 4 * s) ^ (br & 7)) << 3)];
      }
#pragma unroll
      for (int i = 0; i < 4; ++i)
#pragma unroll
        for (int j = 0; j < 4; ++j)
          acc[i][j] = __builtin_amdgcn_mfma_f32_16x16x32_bf16(av[i], bv[j], acc[i][j], 0, 0, 0);
    }
  }
  const int c0 = n0 & 511;
#pragma unroll
  for (int i = 0; i < 4; ++i) {
    const int mbase = m0 + mq + i * 16 + quad * 4;
    const int l0 = mbase & 1023;         // compact row
#pragma unroll
    for (int j = 0; j < 4; ++j) {
      const int nc = c0 + nq + j * 16 + l15;
      const int h = nc >> 6, d = nc & 63;
      if (z == 0) {
        u16* dst = Qb + ((size_t)(b * 8 + h) * 1024 + l0) * 64 + d;
#pragma unroll
        for (int r = 0; r < 4; ++r) dst[(size_t)r * 64] = f2b(acc[i][j][r]);
      } else if (z == 1) {
        u16* dst = Kb + ((size_t)(b * 8 + h) * 1024 + l0) * 64 + d;
#pragma unroll
        for (int r = 0; r < 4; ++r) dst[(size_t)r * 64] = f2b(acc[i][j][r]);
      } else {
        vshort4 vs;
#pragma unroll
        for (int r = 0; r < 4; ++r)
          vs[r] = (short)((l0 + r < nv) ? f2b(acc[i][j][r]) : (u16)0);
        *(vshort4*)(Vtb + ((size_t)(b * 8 + h) * 64 + d) * 1024 + l0) = vs;
      }
    }
  }
}

// ---- fused grid: XCD-batch map; attn + G fully k-compacted ------------------
// kt/kk loops run ceil(nv/64) (~8.5 avg vs 16). Tail: Es zeroed by k<nv
// predicate; dacc mask = kbase<nv bm (R8-verified); V/actc tails are written
// zeros. Block 1536 computes gsums (reads R cross-launch).
__global__ __launch_bounds__(256) void attn_gv_k(
    const u16* __restrict__ Qb, const u16* __restrict__ Kb,
    const u16* __restrict__ Vtb, const u16* __restrict__ actc,
    const int* __restrict__ mask, const int* __restrict__ nvb,
    const float* __restrict__ R,
    u16* __restrict__ AEb, u16* __restrict__ AGb, float* __restrict__ denom) {
  __shared__ __align__(16) u16 POOL[12296];   // 24.6 KB
  const int t = threadIdx.x, w = t >> 6, lane = t & 63;
  const int l15 = lane & 15, quad = lane >> 4;

  if (blockIdx.x == 1536) {
    // ---- gsums: denom[8+b] = sum over valid q of R[q][b] ----
    float* rr = (float*)POOL;   // 4x8 floats
    float a8[8] = {0,0,0,0,0,0,0,0};
    for (int q = t; q < 1024; q += 256)
#pragma unroll
      for (int b = 0; b < 8; ++b)
        if (mask[b * 1024 + q]) a8[b] += R[q * 8 + b];
#pragma unroll
    for (int b = 0; b < 8; ++b) {
#pragma unroll
      for (int off = 32; off > 0; off >>= 1) a8[b] += __shfl_down(a8[b], off);
    }
    if (lane == 0)
#pragma unroll
      for (int b = 0; b < 8; ++b) rr[w * 8 + b] = a8[b];
    __syncthreads();
    if (t < 8) denom[8 + t] = rr[t] + rr[8 + t] + rr[16 + t] + rr[24 + t];
    return;
  }

  const int X = blockIdx.x & 7;      // XCD id (round-robin dispatch, m09)
  const int s = blockIdx.x >> 3;     // slot on this XCD [0,192)
  const int s3 = s % 3, sd3 = s / 3;

  if (s3 == 2) {
    // ---- G-path GEMM, all-compact: AG[(X*1024+qc)][n] =
    //      sum_{kc} actc[X][qc][kc] * Vc[X*512+n][kc]
    u16* As = POOL;           // 64 rows x 64 k  (8 KB)
    u16* Bs = POOL + 4096;    // 128 rows x 64 k (16 KB)
    const int b = X;
    const int q0 = (sd3 >> 2) * 64;          // 16 q-tiles
    const int n0 = (sd3 & 3) * 128;          // 4 n-tiles
    const int nv = nvb[b];
    if (q0 >= nv) return;                    // whole tile is discarded rows
    const int kkmax = (nv + 63) & ~63;       // compact k range (tails are 0)
    const int m0 = b * 1024 + q0;            // compact AGb row base
    const u16* actg = actc + ((size_t)b << 20);
    const int mq = (w >> 1) * 32, nq = (w & 1) * 64;
    const ffrag fz = {0.f, 0.f, 0.f, 0.f};
    ffrag acc[2][4];
#pragma unroll
    for (int i = 0; i < 2; ++i)
#pragma unroll
      for (int j = 0; j < 4; ++j) acc[i][j] = fz;

    for (int kk = 0; kk < kkmax; kk += 64) {
      __syncthreads();
#pragma unroll
      for (int j = 0; j < 2; ++j) {            // A: compact act rows
        const int c = w * 128 + j * 64 + lane;
        const int row = c >> 3, ck = (c & 7) ^ (row & 7);
        gll16(actg + (size_t)(q0 + row) * 1024 + kk + ck * 8,
              &As[(size_t)(w * 128 + j * 64) * 8]);
      }
#pragma unroll
      for (int j = 0; j < 4; ++j) {            // B: compact V columns
        const int c = w * 256 + j * 64 + lane;
        const int row = c >> 3, ck = (c & 7) ^ (row & 7);
        gll16(Vtb + (size_t)(b * 512 + n0 + row) * 1024 + kk + ck * 8,
              &Bs[(size_t)(w * 256 + j * 64) * 8]);
      }
      __syncthreads();
#pragma unroll
      for (int sgm = 0; sgm < 2; ++sgm) {
        bfrag av[2], bv[4];
#pragma unroll
        for (int i = 0; i < 2; ++i) {
          const int ar = mq + i * 16 + l15;
          av[i] = *(const bfrag*)&As[ar * 64 + (((quad + 4 * sgm) ^ (ar & 7)) << 3)];
        }
#pragma unroll
        for (int j = 0; j < 4; ++j) {
          const int br = nq + j * 16 + l15;
          bv[j] = *(const bfrag*)&Bs[br * 64 + (((quad + 4 * sgm) ^ (br & 7)) << 3)];
        }
#pragma unroll
        for (int i = 0; i < 2; ++i)
#pragma unroll
          for (int j = 0; j < 4; ++j)
            acc[i][j] = __builtin_amdgcn_mfma_f32_16x16x32_bf16(av[i], bv[j], acc[i][j], 0, 0, 0);
      }
    }
#pragma unroll
    for (int i = 0; i < 2; ++i) {
      const int mbase = m0 + mq + i * 16 + quad * 4;     // compact row
#pragma unroll
      for (int j = 0; j < 4; ++j) {
        const int n = n0 + nq + j * 16 + l15;
#pragma unroll
        for (int r = 0; r < 4; ++r)
          AGb[(size_t)(mbase + r) * 512 + n] = f2b(acc[i][j][r]);
      }
    }
    return;
  }

  // ---- attention E-path: compact q AND compact k ----
  const int a_ = sd3 * 2 + s3;
  const int qt = a_ & 15;
  const int h = a_ >> 4;
  const int b = X;
  const int bh = X * 8 + h;
  const int nv = nvb[b];
  if (qt * 64 >= nv) return;          // tile entirely masked-q: no output used
  const int ktmax = (nv + 63) >> 6;   // compacted k tiles (~half of 16)
  u16* Ks = POOL;             // 8 KB [kc][d]
  u16* Vs = POOL + 4096;      // 8 KB [d][kc]
  u16* Es = POOL + 8192;      // 8 KB [q][kc]
  float* red4 = (float*)(POOL + 12288);
  const int l31 = lane & 31, hi = lane >> 5;
  const int qsb = w >> 1, msb = w & 1;   // S-phase: q-block, k(m)-block
  const int qpb = w & 1, dpb = w >> 1;   // PV-phase: q-block, d-block (distinct!)

  const u16* Kg = Kb + (size_t)bh * 65536;
  const u16* Vg = Vtb + (size_t)bh * 65536;

  const u16* Qrow = Qb + ((size_t)bh * 1024 + qt * 64 + qsb * 32 + l31) * 64;
  bfrag qf[4];
#pragma unroll
  for (int ko = 0; ko < 4; ++ko) qf[ko] = *(const bfrag*)(Qrow + ko * 16 + hi * 8);

  auto stageK = [&](int kt) {
#pragma unroll
    for (int j = 0; j < 2; ++j) {
      const int c = w * 128 + j * 64 + lane;
      const int row = c >> 3, ck = (c & 7) ^ SWK(row);
      gll16(Kg + (size_t)(kt * 64 + row) * 64 + ck * 8,
            &Ks[(size_t)(w * 128 + j * 64) * 8]);
    }
  };
  auto stageV = [&](int kt) {
#pragma unroll
    for (int j = 0; j < 2; ++j) {
      const int c = w * 128 + j * 64 + lane;
      const int row = c >> 3, ck = (c & 7) ^ SWK(row);
      gll16(Vg + (size_t)row * 1024 + kt * 64 + ck * 8,
            &Vs[(size_t)(w * 128 + j * 64) * 8]);
    }
  };

  stageK(0); stageV(0);
  __syncthreads();

  ffrag16 accE, dacc;
#pragma unroll
  for (int i = 0; i < 16; ++i) { accE[i] = 0.f; dacc[i] = 0.f; }

  for (int kt = 0; kt < ktmax; ++kt) {
    // ---- S-phase: S^T block (m = wave's 32-k block, n = its 32-q block) ----
    ffrag16 st;
#pragma unroll
    for (int i = 0; i < 16; ++i) st[i] = 0.f;
    const int krow = msb * 32 + l31;
    const int kk7 = SWK(krow);
#pragma unroll
    for (int ko = 0; ko < 4; ++ko) {
      bfrag ak = *(const bfrag*)&Ks[krow * 64 + (((ko * 2 + hi) ^ kk7) << 3)];
      st = __builtin_amdgcn_mfma_f32_32x32x16_bf16(ak, qf[ko], st, 0, 0, 0);
    }
    // ---- nonlinearity -> Es; k >= nv forced to 0 (tail tile) ----
    const int qrow = qsb * 32 + l31;
    const int qk7 = SWK(qrow);
#pragma unroll
    for (int g = 0; g < 4; ++g) {
      float ee[4];
      const int kq = kt * 64 + msb * 32 + g * 8 + hi * 4;
#pragma unroll
      for (int r = 0; r < 4; ++r) {
        const float tt = EXP2F(st[4 * g + r] * 0.360673760222f);
        ee[r] = (kq + r < nv) ? EXP2F(RCPF(tt + 1.0f) * -2.88539008178f) : 0.0f;
      }
      const int k0 = msb * 32 + g * 8 + hi * 4;
      *(uint2*)&Es[qrow * 64 + (((k0 >> 3) ^ qk7) << 3) + (k0 & 7)] =
          make_uint2(pk2(ee[0], ee[1]), pk2(ee[2], ee[3]));
    }
    __syncthreads();                   // Es visible; Ks reads done blockwide
    if (kt < ktmax - 1) stageK(kt + 1);

    // ---- PV: distinct quadrant per wave (E-path + denominator only) ----
    const int erow = qpb * 32 + l31;
    const int ek7 = SWK(erow);
    const int vrow = dpb * 32 + l31;
    const int vk7 = SWK(vrow);
#pragma unroll
    for (int ko = 0; ko < 4; ++ko) {
      const int co = ko * 2 + hi;
      bfrag ea = *(const bfrag*)&Es[erow * 64 + ((co ^ ek7) << 3)];
      bfrag bv = *(const bfrag*)&Vs[vrow * 64 + ((co ^ vk7) << 3)];
      accE = __builtin_amdgcn_mfma_f32_32x32x16_bf16(ea, bv, accE, 0, 0, 0);
      if (dpb == 0) {
        const int kbase = kt * 64 + ko * 16 + hi * 8;   // compact k slot
        bfrag bm;
#pragma unroll
        for (int jj = 0; jj < 8; ++jj)
          bm[jj] = (short)((kbase + jj < nv) ? 0x3F80 : 0);
        dacc = __builtin_amdgcn_mfma_f32_32x32x16_bf16(ea, bm, dacc, 0, 0, 0);
      }
    }
    __syncthreads();                   // Vs/Es reads done; stageK drained
    if (kt < ktmax - 1) stageV(kt + 1);
  }

  // ---- epilogue: wave stores its (qpb, dpb) quadrant of AE (compacted rows) -
  const size_t obase = ((size_t)(b * 1024 + qt * 64 + qpb * 32)) * 512
                       + h * 64 + dpb * 32 + l31;
#pragma unroll
  for (int r = 0; r < 16; ++r) {
    const int qloc = (r & 3) + 8 * (r >> 2) + 4 * hi;
    AEb[obase + (size_t)qloc * 512] = f2b(accE[r]);
  }
  // ---- denominator: q-filter is compact index < nv (valid-first order) ----
  float dsumv = 0.0f;
  if (l31 == 0 && dpb == 0) {
    const int cq0 = qt * 64 + qpb * 32 + 4 * hi;
#pragma unroll
    for (int r = 0; r < 16; ++r) {
      const int cq = cq0 + (r & 3) + 8 * (r >> 2);
      dsumv += (cq < nv) ? dacc[r] : 0.0f;
    }
    red4[qpb * 2 + hi] = dsumv;
  }
  __syncthreads();
  if (t == 0) atomicAdd(denom + b, red4[0] + red4[1] + red4[2] + red4[3]);
}

// ---- out = (c1*AE + c2*AG) @ Wo^T in COMPACT row space, scatter via itok ----
__global__ __launch_bounds__(256) void o_proj_k(
    const u16* __restrict__ AEb, const u16* __restrict__ AGb,
    const int* __restrict__ nvb, const int* __restrict__ itok,
    const float* __restrict__ sums,
    const u16* __restrict__ Wb, float* __restrict__ out) {
  const int m0 = blockIdx.x * 128;      // compact row space
  const int n0 = blockIdx.y * 128;
  const int b = m0 >> 10;
  const int q0c = m0 & 1023;
  const int nv = nvb[b];
  const int* it = itok + b * 1024;
  const int t = threadIdx.x, w = t >> 6, lane = t & 63;

  if (q0c >= nv) {
    // ---- all-invalid tile: zero-fill out[token rows][n0..n0+128) ----
    const int row = q0c + (t >> 1);
    const int tok = it[row];
    float4 z4 = make_float4(0.f, 0.f, 0.f, 0.f);
    float* dst = out + ((size_t)(b * 1024 + tok)) * 512 + n0 + (t & 1) * 64;
#pragma unroll
    for (int i = 0; i < 16; ++i) *(float4*)(dst + i * 4) = z4;
    return;
  }

  const float c1 = 0.5f / fmaxf(sums[b], TINYF);
  const float c2 = 0.5f / fmaxf(sums[8 + b], TINYF);
  __shared__ __align__(16) u16 As[128 * 64];
  __shared__ __align__(16) u16 Bs[128 * 64];
  const int l15 = lane & 15, quad = lane >> 4;
  const int mq = (w >> 1) * 64, nq = (w & 1) * 64;

  const ffrag fz = {0.f, 0.f, 0.f, 0.f};
  ffrag acc[4][4];
#pragma unroll
  for (int i = 0; i < 4; ++i)
#pragma unroll
    for (int j = 0; j < 4; ++j) acc[i][j] = fz;

  for (int kk = 0; kk < 512; kk += 64) {
    __syncthreads();
#pragma unroll
    for (int i = 0; i < 4; ++i) {
      const int c = t + i * 256;
      const int row = c >> 3, ck = c & 7;
      const int valid = (q0c + row) < nv;
      const int rowr = valid ? (q0c + row) : 0;        // NaN-proof clamp
      const size_t gofs = (size_t)(b * 1024 + rowr) * 512 + kk + ck * 8;
      uint4 ua = *(const uint4*)(AEb + gofs);
      uint4 ug = *(const uint4*)(AGb + gofs);
      const float a1 = valid ? c1 : 0.0f, a2 = valid ? c2 : 0.0f;
      uint4 res;
      res.x = pk2(a1 * blo(ua.x) + a2 * blo(ug.x), a1 * bhi(ua.x) + a2 * bhi(ug.x));
      res.y = pk2(a1 * blo(ua.y) + a2 * blo(ug.y), a1 * bhi(ua.y) + a2 * bhi(ug.y));
      res.z = pk2(a1 * blo(ua.z) + a2 * blo(ug.z), a1 * bhi(ua.z) + a2 * bhi(ug.z));
      res.w = pk2(a1 * blo(ua.w) + a2 * blo(ug.w), a1 * bhi(ua.w) + a2 * bhi(ug.w));
      *(uint4*)&As[row * 64 + ((ck ^ (row & 7)) << 3)] = res;
    }
#pragma unroll
    for (int j = 0; j < 4; ++j) {
      const int c = w * 256 + j * 64 + lane;
      const int row = c >> 3, ck = (c & 7) ^ (row & 7);
      gll16(Wb + (size_t)(1536 + n0 + row) * 512 + kk + ck * 8,
            &Bs[(size_t)(w * 256 + j * 64) * 8]);
    }
    __syncthreads();
#pragma unroll
    for (int s = 0; s < 2; ++s) {
      bfrag av[4], bv[4];
#pragma unroll
      for (int i = 0; i < 4; ++i) {
        const int ar = mq + i * 16 + l15;
        av[i] = *(const bfrag*)&As[ar * 64 + (((quad + 4 * s) ^ (ar & 7)) << 3)];
        const int br = nq + i * 16 + l15;
        bv[i] = *(const bfrag*)&Bs[br * 64 + (((quad + 4 * s) ^ (br & 7)) << 3)];
      }
#pragma unroll
      for (int i = 0; i < 4; ++i)
#pragma unroll
        for (int j = 0; j < 4; ++j)
          acc[i][j] = __builtin_amdgcn_mfma_f32_16x16x32_bf16(av[i], bv[j], acc[i][j], 0, 0, 0);
    }
  }
  // ---- epilogue: scatter rows to token positions (row-granular) ----
#pragma unroll
  for (int i = 0; i < 4; ++i) {
    const int crow0 = q0c + mq + i * 16 + quad * 4;      // %4 == 0
    const int4 tk = *(const int4*)(it + crow0);
#pragma unroll
    for (int j = 0; j < 4; ++j) {
      const int n = n0 + nq + j * 16 + l15;
      out[(size_t)(b * 1024 + tk.x) * 512 + n] = (crow0     < nv) ? acc[i][j][0] : 0.0f;
      out[(size_t)(b * 1024 + tk.y) * 512 + n] = (crow0 + 1 < nv) ? acc[i][j][1] : 0.0f;
      out[(size_t)(b * 1024 + tk.z) * 512 + n] = (crow0 + 2 < nv) ? acc[i][j][2] : 0.0f;
      out[(size_t)(b * 1024 + tk.w) * 512 + n] = (crow0 + 3 < nv) ? acc[i][j][3] : 0.0f;
    }
  }
}

extern "C" void kernel_launch(void* const* d_in, const int* in_sizes, int n_in,
                              void* d_out, int out_size, void* d_ws, size_t ws_size,
                              hipStream_t stream) {
  const float* x  = (const float*)d_in[0];
  const int* mask = (const int*)d_in[1];
  const float* Wq = (const float*)d_in[2];
  const float* Wk = (const float*)d_in[3];
  const float* Wv = (const float*)d_in[4];
  const float* Wo = (const float*)d_in[5];
  const float* G  = (const float*)d_in[6];
  float* out = (float*)d_out;

  u16* xb   = (u16*)d_ws;                    // 8192*512
  u16* Wb   = xb + (size_t)8192 * 512;       // 2048*512
  u16* Qb   = Wb + (size_t)2048 * 512;       // QSZ (compact rows per batch)
  u16* Kb   = Qb + QSZ;                      // QSZ (compact rows per batch)
  u16* Vtb  = Kb + QSZ;                      // QSZ (compact cols per batch)
  u16* actc = Vtb + QSZ;                     // 8 * 1M (per-batch compacted act)
  u16* AEb  = actc + ((size_t)8 << 20);      // BLE (compact rows per batch)
  u16* AGb  = AEb + BLE;                     // BLE (compact rows per batch)
  float* R  = (float*)(AGb + BLE);           // 1024*8
  float* SUMS = R + 8192;                    // denom[8], gsums[8]
  int* posb = (int*)(SUMS + 16);             // 8*1024 token->compact position
  int* nvb  = posb + 8192;                   // 8 valid counts
  int* itok = nvb + 8;                       // 8*1024 compact->token (inverse)

  prep_k<<<2568, 256, 0, stream>>>(x, Wq, Wk, Wv, Wo, mask, xb, Wb, posb, nvb, itok, SUMS);
  proj_k<<<1792, 256, 0, stream>>>(xb, Wb, G, mask, posb, nvb, itok, actc, R, Qb, Kb, Vtb);
  attn_gv_k<<<1537, 256, 0, stream>>>(Qb, Kb, Vtb, actc, mask, nvb, R, AEb, AGb, SUMS);
  o_proj_k<<<dim3(64, 4), 256, 0, stream>>>(AEb, AGb, nvb, itok, SUMS, Wb, out);
}